// Round 1
// baseline (5018.749 us; speedup 1.0000x reference)
//
#include <hip/hip_runtime.h>
#include <hip/hip_bf16.h>

// Model dims (compile-time constants from the reference)
#define D_MODEL 1024
#define N_LAYER 4
#define D_INNER 2048
#define D_STATE 16
#define D_CONV  4
#define DT_RANK 64
#define SEQ_L   1024

__device__ __forceinline__ float silu_f(float x) {
    return x / (1.0f + __expf(-x));
}
__device__ __forceinline__ float softplus_f(float x) {
    // stable: max(x,0) + log1p(exp(-|x|))
    return fmaxf(x, 0.0f) + log1pf(__expf(-fabsf(x)));
}

// ---------------- embedding gather ----------------
__global__ void embed_kernel(const int* __restrict__ ids,
                             const float* __restrict__ emb,
                             float* __restrict__ hidden) {
    int l = blockIdx.x;
    int t = threadIdx.x;
    int id = ids[l];
    float4 v = *(const float4*)(emb + (size_t)id * D_MODEL + t * 4);
    *(float4*)(hidden + (size_t)l * D_MODEL + t * 4) = v;
}

// ---------------- residual add + RMSNorm ----------------
// res = add ? res + h : h ;  xout = res * rsqrt(mean(res^2)+eps) * w
__global__ void add_rmsnorm_kernel(float* __restrict__ res,
                                   const float* __restrict__ h,
                                   const float* __restrict__ w,
                                   float* __restrict__ xout,
                                   int add) {
    int l = blockIdx.x;
    int t = threadIdx.x;
    size_t base = (size_t)l * D_MODEL + t * 4;
    float4 hv = *(const float4*)(h + base);
    float4 r;
    if (add) {
        r = *(const float4*)(res + base);
        r.x += hv.x; r.y += hv.y; r.z += hv.z; r.w += hv.w;
    } else {
        r = hv;
    }
    *(float4*)(res + base) = r;
    float ss = r.x * r.x + r.y * r.y + r.z * r.z + r.w * r.w;
    // wave64 reduce
    #pragma unroll
    for (int off = 32; off > 0; off >>= 1) ss += __shfl_down(ss, off, 64);
    __shared__ float sred[4];
    if ((t & 63) == 0) sred[t >> 6] = ss;
    __syncthreads();
    float tot = sred[0] + sred[1] + sred[2] + sred[3];
    float scale = rsqrtf(tot * (1.0f / (float)D_MODEL) + 1e-5f);
    float4 wv = *(const float4*)(w + t * 4);
    float4 o;
    o.x = r.x * scale * wv.x;
    o.y = r.y * scale * wv.y;
    o.z = r.z * scale * wv.z;
    o.w = r.w * scale * wv.w;
    *(float4*)(xout + base) = o;
}

// ---------------- generic TN GEMM ----------------
// C[m][n] = dot(A[m][0..K-1] (row stride lda), W[n][0..K-1] (row stride K)) (+epilogue)
// EPI 0: none.  EPI 1: softplus(v + bias[n]).
// Requires: M % 64 == 0, K % 16 == 0, N % 4 == 0. N may be ragged vs 64 grid.
template<int EPI>
__global__ void gemm_tn_kernel(const float* __restrict__ A,
                               const float* __restrict__ W,
                               const float* __restrict__ bias,
                               float* __restrict__ C,
                               int M, int N, int K, int lda) {
    __shared__ float As[16][68];
    __shared__ float Ws[16][68];
    const int t  = threadIdx.x;
    const int m0 = blockIdx.y * 64;
    const int n0 = blockIdx.x * 64;
    const int lrow = t >> 2;         // 0..63
    const int lkq  = (t & 3) * 4;    // 0,4,8,12
    const int tx = t & 15;           // col group 0..15
    const int ty = t >> 4;           // row group 0..15

    const float* Arow = A + (size_t)(m0 + lrow) * lda;
    const int   wr    = n0 + lrow;
    const bool  wvalid = wr < N;
    const float* Wrow = W + (size_t)(wvalid ? wr : 0) * K;

    float acc[4][4] = {};

    for (int k0 = 0; k0 < K; k0 += 16) {
        float4 av = *(const float4*)(Arow + k0 + lkq);
        float4 wv = wvalid ? *(const float4*)(Wrow + k0 + lkq)
                           : make_float4(0.f, 0.f, 0.f, 0.f);
        As[lkq + 0][lrow] = av.x; As[lkq + 1][lrow] = av.y;
        As[lkq + 2][lrow] = av.z; As[lkq + 3][lrow] = av.w;
        Ws[lkq + 0][lrow] = wv.x; Ws[lkq + 1][lrow] = wv.y;
        Ws[lkq + 2][lrow] = wv.z; Ws[lkq + 3][lrow] = wv.w;
        __syncthreads();
        #pragma unroll
        for (int kk = 0; kk < 16; ++kk) {
            float4 a = *(const float4*)&As[kk][ty * 4];
            float4 b = *(const float4*)&Ws[kk][tx * 4];
            acc[0][0] = fmaf(a.x, b.x, acc[0][0]);
            acc[0][1] = fmaf(a.x, b.y, acc[0][1]);
            acc[0][2] = fmaf(a.x, b.z, acc[0][2]);
            acc[0][3] = fmaf(a.x, b.w, acc[0][3]);
            acc[1][0] = fmaf(a.y, b.x, acc[1][0]);
            acc[1][1] = fmaf(a.y, b.y, acc[1][1]);
            acc[1][2] = fmaf(a.y, b.z, acc[1][2]);
            acc[1][3] = fmaf(a.y, b.w, acc[1][3]);
            acc[2][0] = fmaf(a.z, b.x, acc[2][0]);
            acc[2][1] = fmaf(a.z, b.y, acc[2][1]);
            acc[2][2] = fmaf(a.z, b.z, acc[2][2]);
            acc[2][3] = fmaf(a.z, b.w, acc[2][3]);
            acc[3][0] = fmaf(a.w, b.x, acc[3][0]);
            acc[3][1] = fmaf(a.w, b.y, acc[3][1]);
            acc[3][2] = fmaf(a.w, b.z, acc[3][2]);
            acc[3][3] = fmaf(a.w, b.w, acc[3][3]);
        }
        __syncthreads();
    }

    const int colb = n0 + tx * 4;
    if (colb < N) {
        #pragma unroll
        for (int i = 0; i < 4; ++i) {
            int row = m0 + ty * 4 + i;
            float4 v = make_float4(acc[i][0], acc[i][1], acc[i][2], acc[i][3]);
            if (EPI == 1) {
                v.x = softplus_f(v.x + bias[colb + 0]);
                v.y = softplus_f(v.y + bias[colb + 1]);
                v.z = softplus_f(v.z + bias[colb + 2]);
                v.w = softplus_f(v.w + bias[colb + 3]);
            }
            *(float4*)(C + (size_t)row * N + colb) = v;
        }
    }
}

// ---------------- depthwise causal conv (k=4) + silu ----------------
// xp = xz[:, 0:2048] (row stride 4096). u[l][c] = silu(cb[c] + sum_k xp[l+k-3][c]*cw[c][k])
__global__ void conv_silu_kernel(const float* __restrict__ xz,
                                 const float* __restrict__ cw,
                                 const float* __restrict__ cb,
                                 float* __restrict__ u) {
    int idx = blockIdx.x * 256 + threadIdx.x;  // l*2048 + c
    int l = idx >> 11;
    int c = idx & 2047;
    float acc = cb[c];
    float w0 = cw[c * 4 + 0], w1 = cw[c * 4 + 1], w2 = cw[c * 4 + 2], w3 = cw[c * 4 + 3];
    if (l >= 3) acc = fmaf(xz[(size_t)(l - 3) * 4096 + c], w0, acc);
    if (l >= 2) acc = fmaf(xz[(size_t)(l - 2) * 4096 + c], w1, acc);
    if (l >= 1) acc = fmaf(xz[(size_t)(l - 1) * 4096 + c], w2, acc);
    acc = fmaf(xz[(size_t)l * 4096 + c], w3, acc);
    u[idx] = silu_f(acc);
}

// ---------------- selective scan (+ fused silu(z) gate) ----------------
// One thread per channel d (2048 threads). 16 states in registers.
// y[l][d] written into xz[l*4096 + d] (the dead xp half), gated by silu(z = xz[l*4096+2048+d]).
__global__ void scan_kernel(const float* __restrict__ u,
                            const float* __restrict__ dt,
                            const float* __restrict__ xdbl,
                            const float* __restrict__ A_log,
                            const float* __restrict__ Dv,
                            float* __restrict__ xz) {
    int d = blockIdx.x * 256 + threadIdx.x;  // 0..2047
    float Aa[16];
    #pragma unroll
    for (int n = 0; n < 16; ++n) Aa[n] = -__expf(A_log[(size_t)d * 16 + n]);
    float Dd = Dv[d];
    float s[16];
    #pragma unroll
    for (int n = 0; n < 16; ++n) s[n] = 0.0f;

    for (int l = 0; l < SEQ_L; ++l) {
        float dtl = dt[(size_t)l * 2048 + d];
        float ul  = u[(size_t)l * 2048 + d];
        float Bn[16], Cn[16];
        const float* xb = xdbl + (size_t)l * 96;
        *(float4*)&Bn[0]  = *(const float4*)(xb + 64);
        *(float4*)&Bn[4]  = *(const float4*)(xb + 68);
        *(float4*)&Bn[8]  = *(const float4*)(xb + 72);
        *(float4*)&Bn[12] = *(const float4*)(xb + 76);
        *(float4*)&Cn[0]  = *(const float4*)(xb + 80);
        *(float4*)&Cn[4]  = *(const float4*)(xb + 84);
        *(float4*)&Cn[8]  = *(const float4*)(xb + 88);
        *(float4*)&Cn[12] = *(const float4*)(xb + 92);
        float dtu = dtl * ul;
        float acc = 0.0f;
        #pragma unroll
        for (int n = 0; n < 16; ++n) {
            float dA = __expf(dtl * Aa[n]);
            s[n] = fmaf(s[n], dA, dtu * Bn[n]);
            acc = fmaf(s[n], Cn[n], acc);
        }
        float zv = xz[(size_t)l * 4096 + 2048 + d];
        float yv = fmaf(Dd, ul, acc);
        xz[(size_t)l * 4096 + d] = yv * silu_f(zv);
    }
}

extern "C" void kernel_launch(void* const* d_in, const int* in_sizes, int n_in,
                              void* d_out, int out_size, void* d_ws, size_t ws_size,
                              hipStream_t stream) {
    const int*   ids        = (const int*)d_in[0];
    const float* emb        = (const float*)d_in[1];    // (50280, 1024)
    const float* norm_w     = (const float*)d_in[2];    // (4, 1024)
    const float* in_proj_w  = (const float*)d_in[3];    // (4, 4096, 1024)
    const float* conv_w     = (const float*)d_in[4];    // (4, 2048, 4)
    const float* conv_b     = (const float*)d_in[5];    // (4, 2048)
    const float* x_proj_w   = (const float*)d_in[6];    // (4, 96, 2048)
    const float* dt_proj_w  = (const float*)d_in[7];    // (4, 2048, 64)
    const float* dt_proj_b  = (const float*)d_in[8];    // (4, 2048)
    const float* A_log      = (const float*)d_in[9];    // (4, 2048, 16)
    const float* Dv         = (const float*)d_in[10];   // (4, 2048)
    const float* out_proj_w = (const float*)d_in[11];   // (4, 1024, 2048)
    const float* norm_f_w   = (const float*)d_in[12];   // (1024,)
    float* out = (float*)d_out;

    // workspace layout (floats)
    float* ws       = (float*)d_ws;
    float* residual = ws;                       // 1024*1024
    float* hidden   = residual + 1048576;       // 1024*1024
    float* x        = hidden + 1048576;         // 1024*1024
    float* xz       = x + 1048576;              // 1024*4096 (xp half reused for y)
    float* u        = xz + 4194304;             // 1024*2048
    float* dtb      = u + 2097152;              // 1024*2048
    float* xdbl     = dtb + 2097152;            // 1024*96
    // total ~ 11.6M floats = ~46.5 MB

    const int VOCAB = 50280;
    dim3 blk(256);

    embed_kernel<<<dim3(SEQ_L), blk, 0, stream>>>(ids, emb, hidden);

    for (int i = 0; i < N_LAYER; ++i) {
        // residual (+)= hidden ; x = rmsnorm(residual) * norm_w[i]
        add_rmsnorm_kernel<<<dim3(SEQ_L), blk, 0, stream>>>(
            residual, hidden, norm_w + (size_t)i * D_MODEL, x, i == 0 ? 0 : 1);

        // xz = x @ in_proj_w[i]^T : (1024,1024)x(1024,4096)
        gemm_tn_kernel<0><<<dim3(2 * D_INNER / 64, SEQ_L / 64), blk, 0, stream>>>(
            x, in_proj_w + (size_t)i * 2 * D_INNER * D_MODEL, nullptr, xz,
            SEQ_L, 2 * D_INNER, D_MODEL, D_MODEL);

        // u = silu(depthwise_conv(xp) + cb)
        conv_silu_kernel<<<dim3(SEQ_L * D_INNER / 256), blk, 0, stream>>>(
            xz, conv_w + (size_t)i * D_INNER * D_CONV, conv_b + (size_t)i * D_INNER, u);

        // xdbl = u @ x_proj_w[i]^T : (1024,2048)x(2048,96)
        gemm_tn_kernel<0><<<dim3(2, SEQ_L / 64), blk, 0, stream>>>(
            u, x_proj_w + (size_t)i * 96 * D_INNER, nullptr, xdbl,
            SEQ_L, 96, D_INNER, D_INNER);

        // dt = softplus(dt_r @ dt_proj_w[i]^T + dt_b) : (1024,64)x(64,2048)
        gemm_tn_kernel<1><<<dim3(D_INNER / 64, SEQ_L / 64), blk, 0, stream>>>(
            xdbl, dt_proj_w + (size_t)i * D_INNER * DT_RANK,
            dt_proj_b + (size_t)i * D_INNER, dtb,
            SEQ_L, D_INNER, DT_RANK, 96);

        // selective scan + silu(z) gate -> y stored in xz[:, 0:2048]
        scan_kernel<<<dim3(D_INNER / 256), blk, 0, stream>>>(
            u, dtb, xdbl, A_log + (size_t)i * D_INNER * D_STATE,
            Dv + (size_t)i * D_INNER, xz);

        // hidden = y @ out_proj_w[i]^T : (1024,2048)x(2048,1024)
        gemm_tn_kernel<0><<<dim3(D_MODEL / 64, SEQ_L / 64), blk, 0, stream>>>(
            xz, out_proj_w + (size_t)i * D_MODEL * D_INNER, nullptr, hidden,
            SEQ_L, D_MODEL, D_INNER, 2 * D_INNER);
    }

    // final: residual += hidden ; hf = rmsnorm(residual) * norm_f_w  (into x)
    add_rmsnorm_kernel<<<dim3(SEQ_L), blk, 0, stream>>>(
        residual, hidden, norm_f_w, x, 1);

    // logits = hf @ embedding^T : (1024,1024)x(1024,50280)
    gemm_tn_kernel<0><<<dim3((VOCAB + 63) / 64, SEQ_L / 64), blk, 0, stream>>>(
        x, emb, nullptr, out, SEQ_L, VOCAB, D_MODEL, D_MODEL);
}

// Round 2
// 3671.201 us; speedup vs baseline: 1.3671x; 1.3671x over previous
//
#include <hip/hip_runtime.h>
#include <hip/hip_bf16.h>

#define D_MODEL 1024
#define N_LAYER 4
#define D_INNER 2048
#define D_STATE 16
#define D_CONV  4
#define DT_RANK 64
#define SEQ_L   1024
#define VOCAB   50280

typedef __attribute__((ext_vector_type(8))) short short8;
typedef __attribute__((ext_vector_type(4))) float f32x4;

__device__ __forceinline__ float silu_f(float x) {
    return x / (1.0f + __expf(-x));
}
__device__ __forceinline__ float softplus_f(float x) {
    return fmaxf(x, 0.0f) + log1pf(__expf(-fabsf(x)));
}
__device__ __forceinline__ ushort f2bf(float f) {
    union { float f; unsigned u; } uf; uf.f = f;
    unsigned r = uf.u + 0x7FFF + ((uf.u >> 16) & 1);   // RNE
    return (ushort)(r >> 16);
}

// ---------------- fp32 -> bf16 bulk convert ----------------
__global__ void f32_to_bf16_kernel(const float* __restrict__ in,
                                   ushort* __restrict__ out, int n4) {
    int i = blockIdx.x * 256 + threadIdx.x;
    if (i >= n4) return;
    float4 v = *(const float4*)(in + (size_t)i * 4);
    ushort4 o;
    o.x = f2bf(v.x); o.y = f2bf(v.y); o.z = f2bf(v.z); o.w = f2bf(v.w);
    *(ushort4*)(out + (size_t)i * 4) = o;
}

// ---------------- embedding gather ----------------
__global__ void embed_kernel(const int* __restrict__ ids,
                             const float* __restrict__ emb,
                             float* __restrict__ hidden) {
    int l = blockIdx.x;
    int t = threadIdx.x;
    int id = ids[l];
    float4 v = *(const float4*)(emb + (size_t)id * D_MODEL + t * 4);
    *(float4*)(hidden + (size_t)l * D_MODEL + t * 4) = v;
}

// ---------------- residual add + RMSNorm -> bf16 x ----------------
__global__ void add_rmsnorm_kernel(float* __restrict__ res,
                                   const float* __restrict__ h,
                                   const float* __restrict__ w,
                                   ushort* __restrict__ xout,
                                   int add) {
    int l = blockIdx.x;
    int t = threadIdx.x;
    size_t base = (size_t)l * D_MODEL + t * 4;
    float4 hv = *(const float4*)(h + base);
    float4 r;
    if (add) {
        r = *(const float4*)(res + base);
        r.x += hv.x; r.y += hv.y; r.z += hv.z; r.w += hv.w;
    } else {
        r = hv;
    }
    *(float4*)(res + base) = r;
    float ss = r.x * r.x + r.y * r.y + r.z * r.z + r.w * r.w;
    #pragma unroll
    for (int off = 32; off > 0; off >>= 1) ss += __shfl_down(ss, off, 64);
    __shared__ float sred[4];
    if ((t & 63) == 0) sred[t >> 6] = ss;
    __syncthreads();
    float tot = sred[0] + sred[1] + sred[2] + sred[3];
    float scale = rsqrtf(tot * (1.0f / (float)D_MODEL) + 1e-5f);
    float4 wv = *(const float4*)(w + t * 4);
    ushort4 o;
    o.x = f2bf(r.x * scale * wv.x);
    o.y = f2bf(r.y * scale * wv.y);
    o.z = f2bf(r.z * scale * wv.z);
    o.w = f2bf(r.w * scale * wv.w);
    *(ushort4*)(xout + base) = o;
}

// ---------------- bf16 MFMA TN GEMM ----------------
// C[m][n] = sum_k A[m][k] * W[n][k].  A: [M][lda] bf16, W: [N][K] bf16 (row-major,
// K-contiguous), C: [M][ldc] fp32.  Tile 128x128, BK=32, 4 waves (2x2), each wave
// 64x64 via 4x4 fragments of mfma_f32_16x16x32_bf16. Reg-staged LDS, +16B row pad.
// Requires M%128==0, K%32==0. N may be ragged.
__global__ void gemm_bf16_mfma_kernel(const ushort* __restrict__ A,
                                      const ushort* __restrict__ W,
                                      float* __restrict__ C,
                                      int N, int K, int lda, int ldc) {
    __shared__ ushort As[128][40];   // 32 data + 8 pad -> 80B row stride
    __shared__ ushort Ws[128][40];
    const int t  = threadIdx.x;
    const int m0 = blockIdx.y * 128;
    const int n0 = blockIdx.x * 128;

    // staging map: thread t -> row t>>1, 16-element half (t&1)
    const int srow = t >> 1;
    const int skc  = (t & 1) * 16;
    const ushort* Ag = A + (size_t)(m0 + srow) * lda + skc;
    const bool wv = (n0 + srow) < N;
    const ushort* Wg = W + (size_t)(wv ? (n0 + srow) : 0) * K + skc;

    // compute map
    const int lane = t & 63;
    const int wm = (t >> 7) & 1;
    const int wn = (t >> 6) & 1;
    const int lr = lane & 15;
    const int lk = lane >> 4;

    f32x4 acc[4][4] = {};
    const short8 zero = {0, 0, 0, 0, 0, 0, 0, 0};

    short8 a0 = *(const short8*)(Ag);
    short8 a1 = *(const short8*)(Ag + 8);
    short8 w0 = wv ? *(const short8*)(Wg)     : zero;
    short8 w1 = wv ? *(const short8*)(Wg + 8) : zero;

    for (int k0 = 0;;) {
        *(short8*)&As[srow][skc]     = a0;
        *(short8*)&As[srow][skc + 8] = a1;
        *(short8*)&Ws[srow][skc]     = w0;
        *(short8*)&Ws[srow][skc + 8] = w1;
        __syncthreads();

        k0 += 32;
        const bool more = k0 < K;
        if (more) {
            a0 = *(const short8*)(Ag + k0);
            a1 = *(const short8*)(Ag + k0 + 8);
            if (wv) {
                w0 = *(const short8*)(Wg + k0);
                w1 = *(const short8*)(Wg + k0 + 8);
            }
        }

        short8 af[4], bfr[4];
        #pragma unroll
        for (int m = 0; m < 4; ++m)
            af[m] = *(const short8*)&As[wm * 64 + m * 16 + lr][lk * 8];
        #pragma unroll
        for (int n = 0; n < 4; ++n)
            bfr[n] = *(const short8*)&Ws[wn * 64 + n * 16 + lr][lk * 8];
        #pragma unroll
        for (int m = 0; m < 4; ++m)
            #pragma unroll
            for (int n = 0; n < 4; ++n)
                acc[m][n] = __builtin_amdgcn_mfma_f32_16x16x32_bf16(
                    af[m], bfr[n], acc[m][n], 0, 0, 0);

        if (!more) break;
        __syncthreads();
    }

    // epilogue: D lane mapping col = lane&15, row = (lane>>4)*4 + reg
    #pragma unroll
    for (int m = 0; m < 4; ++m) {
        const int row = m0 + wm * 64 + m * 16 + lk * 4;
        #pragma unroll
        for (int n = 0; n < 4; ++n) {
            const int col = n0 + wn * 64 + n * 16 + lr;
            if (col < N) {
                #pragma unroll
                for (int r = 0; r < 4; ++r)
                    C[(size_t)(row + r) * ldc + col] = acc[m][n][r];
            }
        }
    }
}

// ---------------- fp32 TN GEMM (kept for dt_proj only) ----------------
template<int EPI>
__global__ void gemm_tn_kernel(const float* __restrict__ A,
                               const float* __restrict__ W,
                               const float* __restrict__ bias,
                               float* __restrict__ C,
                               int M, int N, int K, int lda) {
    __shared__ float As[16][68];
    __shared__ float Ws[16][68];
    const int t  = threadIdx.x;
    const int m0 = blockIdx.y * 64;
    const int n0 = blockIdx.x * 64;
    const int lrow = t >> 2;
    const int lkq  = (t & 3) * 4;
    const int tx = t & 15;
    const int ty = t >> 4;

    const float* Arow = A + (size_t)(m0 + lrow) * lda;
    const int   wr    = n0 + lrow;
    const bool  wvalid = wr < N;
    const float* Wrow = W + (size_t)(wvalid ? wr : 0) * K;

    float acc[4][4] = {};
    for (int k0 = 0; k0 < K; k0 += 16) {
        float4 av = *(const float4*)(Arow + k0 + lkq);
        float4 wv = wvalid ? *(const float4*)(Wrow + k0 + lkq)
                           : make_float4(0.f, 0.f, 0.f, 0.f);
        As[lkq + 0][lrow] = av.x; As[lkq + 1][lrow] = av.y;
        As[lkq + 2][lrow] = av.z; As[lkq + 3][lrow] = av.w;
        Ws[lkq + 0][lrow] = wv.x; Ws[lkq + 1][lrow] = wv.y;
        Ws[lkq + 2][lrow] = wv.z; Ws[lkq + 3][lrow] = wv.w;
        __syncthreads();
        #pragma unroll
        for (int kk = 0; kk < 16; ++kk) {
            float4 a = *(const float4*)&As[kk][ty * 4];
            float4 b = *(const float4*)&Ws[kk][tx * 4];
            #pragma unroll
            for (int i = 0; i < 4; ++i) {
                float ai = (i == 0) ? a.x : (i == 1) ? a.y : (i == 2) ? a.z : a.w;
                acc[i][0] = fmaf(ai, b.x, acc[i][0]);
                acc[i][1] = fmaf(ai, b.y, acc[i][1]);
                acc[i][2] = fmaf(ai, b.z, acc[i][2]);
                acc[i][3] = fmaf(ai, b.w, acc[i][3]);
            }
        }
        __syncthreads();
    }

    const int colb = n0 + tx * 4;
    if (colb < N) {
        #pragma unroll
        for (int i = 0; i < 4; ++i) {
            int row = m0 + ty * 4 + i;
            float4 v = make_float4(acc[i][0], acc[i][1], acc[i][2], acc[i][3]);
            if (EPI == 1) {
                v.x = softplus_f(v.x + bias[colb + 0]);
                v.y = softplus_f(v.y + bias[colb + 1]);
                v.z = softplus_f(v.z + bias[colb + 2]);
                v.w = softplus_f(v.w + bias[colb + 3]);
            }
            *(float4*)(C + (size_t)row * N + colb) = v;
        }
    }
}

// ---------------- depthwise causal conv (k=4) + silu ----------------
// writes u (fp32, for scan) and u_b (bf16, for x_proj MFMA)
__global__ void conv_silu_kernel(const float* __restrict__ xz,
                                 const float* __restrict__ cw,
                                 const float* __restrict__ cb,
                                 float* __restrict__ u,
                                 ushort* __restrict__ u_b) {
    int idx = blockIdx.x * 256 + threadIdx.x;
    int l = idx >> 11;
    int c = idx & 2047;
    float acc = cb[c];
    float w0 = cw[c * 4 + 0], w1 = cw[c * 4 + 1], w2 = cw[c * 4 + 2], w3 = cw[c * 4 + 3];
    if (l >= 3) acc = fmaf(xz[(size_t)(l - 3) * 4096 + c], w0, acc);
    if (l >= 2) acc = fmaf(xz[(size_t)(l - 2) * 4096 + c], w1, acc);
    if (l >= 1) acc = fmaf(xz[(size_t)(l - 1) * 4096 + c], w2, acc);
    acc = fmaf(xz[(size_t)l * 4096 + c], w3, acc);
    float s = silu_f(acc);
    u[idx] = s;
    u_b[idx] = f2bf(s);
}

// ---------------- selective scan, lane-parallel over states ----------------
// lane layout: n = lane&15 (state), dg = lane>>4 (channel-in-wave 0..3)
// d = blockIdx.x*16 + wave*4 + dg.  y reduced over 16 lanes via shfl_xor.
// Output: yb (bf16) = y * silu(z), consumed by out_proj MFMA.
__global__ void scan_kernel(const float* __restrict__ u,
                            const float* __restrict__ dt,
                            const float* __restrict__ xdbl,
                            const float* __restrict__ A_log,
                            const float* __restrict__ Dv,
                            const float* __restrict__ xz,
                            ushort* __restrict__ yb) {
    const int t = threadIdx.x;
    const int lane = t & 63;
    const int n  = lane & 15;
    const int dg = lane >> 4;
    const int wave = t >> 6;
    const int d = blockIdx.x * 16 + wave * 4 + dg;

    const float Aa = -__expf(A_log[(size_t)d * 16 + n]);
    const float Dd = Dv[d];
    float s = 0.0f;

    for (int l = 0; l < SEQ_L; ++l) {
        const float dtl = dt[(size_t)l * 2048 + d];
        const float ul  = u[(size_t)l * 2048 + d];
        const float Bn  = xdbl[(size_t)l * 96 + 64 + n];
        const float Cn  = xdbl[(size_t)l * 96 + 80 + n];
        const float zv  = xz[(size_t)l * 4096 + 2048 + d];

        const float dA = __expf(dtl * Aa);
        s = fmaf(s, dA, dtl * ul * Bn);
        float y = s * Cn;
        y += __shfl_xor(y, 8, 64);
        y += __shfl_xor(y, 4, 64);
        y += __shfl_xor(y, 2, 64);
        y += __shfl_xor(y, 1, 64);
        if (n == 0) {
            float yv = (y + Dd * ul) * silu_f(zv);
            yb[(size_t)l * 2048 + d] = f2bf(yv);
        }
    }
}

extern "C" void kernel_launch(void* const* d_in, const int* in_sizes, int n_in,
                              void* d_out, int out_size, void* d_ws, size_t ws_size,
                              hipStream_t stream) {
    const int*   ids        = (const int*)d_in[0];
    const float* emb        = (const float*)d_in[1];
    const float* norm_w     = (const float*)d_in[2];
    const float* in_proj_w  = (const float*)d_in[3];
    const float* conv_w     = (const float*)d_in[4];
    const float* conv_b     = (const float*)d_in[5];
    const float* x_proj_w   = (const float*)d_in[6];
    const float* dt_proj_w  = (const float*)d_in[7];
    const float* dt_proj_b  = (const float*)d_in[8];
    const float* A_log      = (const float*)d_in[9];
    const float* Dv         = (const float*)d_in[10];
    const float* out_proj_w = (const float*)d_in[11];
    const float* norm_f_w   = (const float*)d_in[12];
    float* out = (float*)d_out;

    // ---- workspace layout ----
    char* p = (char*)d_ws;
    ushort* emb_b  = (ushort*)p; p += (size_t)VOCAB * D_MODEL * 2;          // 103.0 MB
    ushort* inw_b  = (ushort*)p; p += (size_t)N_LAYER * 4096 * 1024 * 2;    // 33.6 MB
    ushort* outw_b = (ushort*)p; p += (size_t)N_LAYER * 1024 * 2048 * 2;    // 16.8 MB
    ushort* xpw_b  = (ushort*)p; p += (size_t)N_LAYER * 96 * 2048 * 2;      //  1.6 MB
    float* residual = (float*)p; p += (size_t)SEQ_L * D_MODEL * 4;          //  4.2 MB
    float* hidden   = (float*)p; p += (size_t)SEQ_L * D_MODEL * 4;          //  4.2 MB
    ushort* xb      = (ushort*)p; p += (size_t)SEQ_L * D_MODEL * 2;         //  2.1 MB
    float* xz       = (float*)p; p += (size_t)SEQ_L * 4096 * 4;             // 16.8 MB
    float* u        = (float*)p; p += (size_t)SEQ_L * 2048 * 4;             //  8.4 MB
    ushort* u_b     = (ushort*)p; p += (size_t)SEQ_L * 2048 * 2;            //  4.2 MB
    float* dtb      = (float*)p; p += (size_t)SEQ_L * 2048 * 4;             //  8.4 MB
    float* xdbl     = (float*)p; p += (size_t)SEQ_L * 96 * 4;               //  0.4 MB
    ushort* yb      = (ushort*)p; p += (size_t)SEQ_L * 2048 * 2;            //  4.2 MB

    dim3 blk(256);

    // ---- weight conversions (once per launch) ----
    f32_to_bf16_kernel<<<dim3(VOCAB * D_MODEL / 4 / 256), blk, 0, stream>>>(
        emb, emb_b, VOCAB * D_MODEL / 4);
    f32_to_bf16_kernel<<<dim3(N_LAYER * 4096 * 1024 / 4 / 256), blk, 0, stream>>>(
        in_proj_w, inw_b, N_LAYER * 4096 * 1024 / 4);
    f32_to_bf16_kernel<<<dim3(N_LAYER * 1024 * 2048 / 4 / 256), blk, 0, stream>>>(
        out_proj_w, outw_b, N_LAYER * 1024 * 2048 / 4);
    f32_to_bf16_kernel<<<dim3(N_LAYER * 96 * 2048 / 4 / 256), blk, 0, stream>>>(
        x_proj_w, xpw_b, N_LAYER * 96 * 2048 / 4);

    embed_kernel<<<dim3(SEQ_L), blk, 0, stream>>>(ids, emb, hidden);

    for (int i = 0; i < N_LAYER; ++i) {
        add_rmsnorm_kernel<<<dim3(SEQ_L), blk, 0, stream>>>(
            residual, hidden, norm_w + (size_t)i * D_MODEL, xb, i == 0 ? 0 : 1);

        // xz = x @ in_proj^T : M=1024 N=4096 K=1024
        gemm_bf16_mfma_kernel<<<dim3(4096 / 128, SEQ_L / 128), blk, 0, stream>>>(
            xb, inw_b + (size_t)i * 4096 * 1024, xz, 4096, 1024, 1024, 4096);

        conv_silu_kernel<<<dim3(SEQ_L * D_INNER / 256), blk, 0, stream>>>(
            xz, conv_w + (size_t)i * D_INNER * D_CONV, conv_b + (size_t)i * D_INNER,
            u, u_b);

        // xdbl = u @ x_proj^T : M=1024 N=96 K=2048
        gemm_bf16_mfma_kernel<<<dim3(1, SEQ_L / 128), blk, 0, stream>>>(
            u_b, xpw_b + (size_t)i * 96 * 2048, xdbl, 96, 2048, 2048, 96);

        // dt = softplus(dt_r @ dt_proj^T + b) : fp32, M=1024 N=2048 K=64 (lda=96)
        gemm_tn_kernel<1><<<dim3(D_INNER / 64, SEQ_L / 64), blk, 0, stream>>>(
            xdbl, dt_proj_w + (size_t)i * D_INNER * DT_RANK,
            dt_proj_b + (size_t)i * D_INNER, dtb,
            SEQ_L, D_INNER, DT_RANK, 96);

        scan_kernel<<<dim3(D_INNER / 16), blk, 0, stream>>>(
            u, dtb, xdbl, A_log + (size_t)i * D_INNER * D_STATE,
            Dv + (size_t)i * D_INNER, xz, yb);

        // hidden = y @ out_proj^T : M=1024 N=1024 K=2048
        gemm_bf16_mfma_kernel<<<dim3(1024 / 128, SEQ_L / 128), blk, 0, stream>>>(
            yb, outw_b + (size_t)i * 1024 * 2048, hidden, 1024, 2048, 2048, 1024);
    }

    // final rmsnorm -> bf16 hf (reuse xb)
    add_rmsnorm_kernel<<<dim3(SEQ_L), blk, 0, stream>>>(
        residual, hidden, norm_f_w, xb, 1);

    // logits = hf @ emb^T : M=1024 N=50280 K=1024
    gemm_bf16_mfma_kernel<<<dim3((VOCAB + 127) / 128, SEQ_L / 128), blk, 0, stream>>>(
        xb, emb_b, out, VOCAB, 1024, 1024, VOCAB);
}

// Round 3
// 1038.663 us; speedup vs baseline: 4.8319x; 3.5345x over previous
//
#include <hip/hip_runtime.h>
#include <hip/hip_bf16.h>

#define D_MODEL 1024
#define N_LAYER 4
#define D_INNER 2048
#define D_STATE 16
#define D_CONV  4
#define DT_RANK 64
#define SEQ_L   1024
#define VOCAB   50280
#define NCHUNK  16
#define CLEN    64

typedef __attribute__((ext_vector_type(8))) short short8;
typedef __attribute__((ext_vector_type(4))) float f32x4;

__device__ __forceinline__ float silu_f(float x) {
    return x / (1.0f + __expf(-x));
}
__device__ __forceinline__ float softplus_f(float x) {
    return fmaxf(x, 0.0f) + log1pf(__expf(-fabsf(x)));
}
__device__ __forceinline__ ushort f2bf(float f) {
    union { float f; unsigned u; } uf; uf.f = f;
    unsigned r = uf.u + 0x7FFF + ((uf.u >> 16) & 1);   // RNE
    return (ushort)(r >> 16);
}

// ---------------- fp32 -> bf16 bulk convert ----------------
__global__ void f32_to_bf16_kernel(const float* __restrict__ in,
                                   ushort* __restrict__ out, int n4) {
    int i = blockIdx.x * 256 + threadIdx.x;
    if (i >= n4) return;
    float4 v = *(const float4*)(in + (size_t)i * 4);
    ushort4 o;
    o.x = f2bf(v.x); o.y = f2bf(v.y); o.z = f2bf(v.z); o.w = f2bf(v.w);
    *(ushort4*)(out + (size_t)i * 4) = o;
}

__global__ void zero_kernel(float* __restrict__ p, int n4) {
    int i = blockIdx.x * 256 + threadIdx.x;
    if (i < n4) *(float4*)(p + (size_t)i * 4) = make_float4(0.f, 0.f, 0.f, 0.f);
}

// ---------------- embedding gather ----------------
__global__ void embed_kernel(const int* __restrict__ ids,
                             const float* __restrict__ emb,
                             float* __restrict__ hidden) {
    int l = blockIdx.x;
    int t = threadIdx.x;
    int id = ids[l];
    float4 v = *(const float4*)(emb + (size_t)id * D_MODEL + t * 4);
    *(float4*)(hidden + (size_t)l * D_MODEL + t * 4) = v;
}

// ---------------- residual add + RMSNorm -> bf16 x ----------------
__global__ void add_rmsnorm_kernel(float* __restrict__ res,
                                   const float* __restrict__ h,
                                   const float* __restrict__ w,
                                   ushort* __restrict__ xout,
                                   int add) {
    int l = blockIdx.x;
    int t = threadIdx.x;
    size_t base = (size_t)l * D_MODEL + t * 4;
    float4 hv = *(const float4*)(h + base);
    float4 r;
    if (add) {
        r = *(const float4*)(res + base);
        r.x += hv.x; r.y += hv.y; r.z += hv.z; r.w += hv.w;
    } else {
        r = hv;
    }
    *(float4*)(res + base) = r;
    float ss = r.x * r.x + r.y * r.y + r.z * r.z + r.w * r.w;
    #pragma unroll
    for (int off = 32; off > 0; off >>= 1) ss += __shfl_down(ss, off, 64);
    __shared__ float sred[4];
    if ((t & 63) == 0) sred[t >> 6] = ss;
    __syncthreads();
    float tot = sred[0] + sred[1] + sred[2] + sred[3];
    float scale = rsqrtf(tot * (1.0f / (float)D_MODEL) + 1e-5f);
    float4 wv = *(const float4*)(w + t * 4);
    ushort4 o;
    o.x = f2bf(r.x * scale * wv.x);
    o.y = f2bf(r.y * scale * wv.y);
    o.z = f2bf(r.z * scale * wv.z);
    o.w = f2bf(r.w * scale * wv.w);
    *(ushort4*)(xout + base) = o;
}

// ---------------- bf16 MFMA TN GEMM (optional split-K w/ atomics) ----------------
// C[m][n] (+)= sum_{k in [kbeg,kend)} A[m][k] * W[n][k]
// kbeg = blockIdx.z * kchunk. ATOMIC=1 -> atomicAdd epilogue (C must be pre-zeroed).
template<int ATOMIC>
__global__ void gemm_bf16_mfma_kernel(const ushort* __restrict__ A,
                                      const ushort* __restrict__ W,
                                      float* __restrict__ C,
                                      int N, int K, int lda, int ldc, int kchunk) {
    __shared__ ushort As[128][40];
    __shared__ ushort Ws[128][40];
    const int t  = threadIdx.x;
    const int m0 = blockIdx.y * 128;
    const int n0 = blockIdx.x * 128;
    const int kbeg = blockIdx.z * kchunk;
    const int kend = kbeg + kchunk;

    const int srow = t >> 1;
    const int skc  = (t & 1) * 16;
    const ushort* Ag = A + (size_t)(m0 + srow) * lda + skc;
    const bool wv = (n0 + srow) < N;
    const ushort* Wg = W + (size_t)(wv ? (n0 + srow) : 0) * K + skc;

    const int lane = t & 63;
    const int wm = (t >> 7) & 1;
    const int wn = (t >> 6) & 1;
    const int lr = lane & 15;
    const int lk = lane >> 4;

    f32x4 acc[4][4] = {};
    const short8 zero = {0, 0, 0, 0, 0, 0, 0, 0};

    short8 a0 = *(const short8*)(Ag + kbeg);
    short8 a1 = *(const short8*)(Ag + kbeg + 8);
    short8 w0 = wv ? *(const short8*)(Wg + kbeg)     : zero;
    short8 w1 = wv ? *(const short8*)(Wg + kbeg + 8) : zero;

    for (int k0 = kbeg;;) {
        *(short8*)&As[srow][skc]     = a0;
        *(short8*)&As[srow][skc + 8] = a1;
        *(short8*)&Ws[srow][skc]     = w0;
        *(short8*)&Ws[srow][skc + 8] = w1;
        __syncthreads();

        k0 += 32;
        const bool more = k0 < kend;
        if (more) {
            a0 = *(const short8*)(Ag + k0);
            a1 = *(const short8*)(Ag + k0 + 8);
            if (wv) {
                w0 = *(const short8*)(Wg + k0);
                w1 = *(const short8*)(Wg + k0 + 8);
            }
        }

        short8 af[4], bfr[4];
        #pragma unroll
        for (int m = 0; m < 4; ++m)
            af[m] = *(const short8*)&As[wm * 64 + m * 16 + lr][lk * 8];
        #pragma unroll
        for (int n = 0; n < 4; ++n)
            bfr[n] = *(const short8*)&Ws[wn * 64 + n * 16 + lr][lk * 8];
        #pragma unroll
        for (int m = 0; m < 4; ++m)
            #pragma unroll
            for (int n = 0; n < 4; ++n)
                acc[m][n] = __builtin_amdgcn_mfma_f32_16x16x32_bf16(
                    af[m], bfr[n], acc[m][n], 0, 0, 0);

        if (!more) break;
        __syncthreads();
    }

    #pragma unroll
    for (int m = 0; m < 4; ++m) {
        const int row = m0 + wm * 64 + m * 16 + lk * 4;
        #pragma unroll
        for (int n = 0; n < 4; ++n) {
            const int col = n0 + wn * 64 + n * 16 + lr;
            if (col < N) {
                #pragma unroll
                for (int r = 0; r < 4; ++r) {
                    if (ATOMIC)
                        atomicAdd(&C[(size_t)(row + r) * ldc + col], acc[m][n][r]);
                    else
                        C[(size_t)(row + r) * ldc + col] = acc[m][n][r];
                }
            }
        }
    }
}

// ---------------- fp32 TN GEMM (dt_proj only) ----------------
template<int EPI>
__global__ void gemm_tn_kernel(const float* __restrict__ A,
                               const float* __restrict__ W,
                               const float* __restrict__ bias,
                               float* __restrict__ C,
                               int M, int N, int K, int lda) {
    __shared__ float As[16][68];
    __shared__ float Ws[16][68];
    const int t  = threadIdx.x;
    const int m0 = blockIdx.y * 64;
    const int n0 = blockIdx.x * 64;
    const int lrow = t >> 2;
    const int lkq  = (t & 3) * 4;
    const int tx = t & 15;
    const int ty = t >> 4;

    const float* Arow = A + (size_t)(m0 + lrow) * lda;
    const int   wr    = n0 + lrow;
    const bool  wvalid = wr < N;
    const float* Wrow = W + (size_t)(wvalid ? wr : 0) * K;

    float acc[4][4] = {};
    for (int k0 = 0; k0 < K; k0 += 16) {
        float4 av = *(const float4*)(Arow + k0 + lkq);
        float4 wv = wvalid ? *(const float4*)(Wrow + k0 + lkq)
                           : make_float4(0.f, 0.f, 0.f, 0.f);
        As[lkq + 0][lrow] = av.x; As[lkq + 1][lrow] = av.y;
        As[lkq + 2][lrow] = av.z; As[lkq + 3][lrow] = av.w;
        Ws[lkq + 0][lrow] = wv.x; Ws[lkq + 1][lrow] = wv.y;
        Ws[lkq + 2][lrow] = wv.z; Ws[lkq + 3][lrow] = wv.w;
        __syncthreads();
        #pragma unroll
        for (int kk = 0; kk < 16; ++kk) {
            float4 a = *(const float4*)&As[kk][ty * 4];
            float4 b = *(const float4*)&Ws[kk][tx * 4];
            #pragma unroll
            for (int i = 0; i < 4; ++i) {
                float ai = (i == 0) ? a.x : (i == 1) ? a.y : (i == 2) ? a.z : a.w;
                acc[i][0] = fmaf(ai, b.x, acc[i][0]);
                acc[i][1] = fmaf(ai, b.y, acc[i][1]);
                acc[i][2] = fmaf(ai, b.z, acc[i][2]);
                acc[i][3] = fmaf(ai, b.w, acc[i][3]);
            }
        }
        __syncthreads();
    }

    const int colb = n0 + tx * 4;
    if (colb < N) {
        #pragma unroll
        for (int i = 0; i < 4; ++i) {
            int row = m0 + ty * 4 + i;
            float4 v = make_float4(acc[i][0], acc[i][1], acc[i][2], acc[i][3]);
            if (EPI == 1) {
                v.x = softplus_f(v.x + bias[colb + 0]);
                v.y = softplus_f(v.y + bias[colb + 1]);
                v.z = softplus_f(v.z + bias[colb + 2]);
                v.w = softplus_f(v.w + bias[colb + 3]);
            }
            *(float4*)(C + (size_t)row * N + colb) = v;
        }
    }
}

// ---------------- depthwise causal conv (k=4) + silu ----------------
__global__ void conv_silu_kernel(const float* __restrict__ xz,
                                 const float* __restrict__ cw,
                                 const float* __restrict__ cb,
                                 float* __restrict__ u,
                                 ushort* __restrict__ u_b) {
    int idx = blockIdx.x * 256 + threadIdx.x;
    int l = idx >> 11;
    int c = idx & 2047;
    float acc = cb[c];
    float w0 = cw[c * 4 + 0], w1 = cw[c * 4 + 1], w2 = cw[c * 4 + 2], w3 = cw[c * 4 + 3];
    if (l >= 3) acc = fmaf(xz[(size_t)(l - 3) * 4096 + c], w0, acc);
    if (l >= 2) acc = fmaf(xz[(size_t)(l - 2) * 4096 + c], w1, acc);
    if (l >= 1) acc = fmaf(xz[(size_t)(l - 1) * 4096 + c], w2, acc);
    acc = fmaf(xz[(size_t)l * 4096 + c], w3, acc);
    float s = silu_f(acc);
    u[idx] = s;
    u_b[idx] = f2bf(s);
}

// ---------------- chunked selective scan ----------------
// Pass A: thread per (d, chunk). Local scan (s=0 start) over CLEN steps.
// Writes yloc (into dead xp half of xz), cumdt[l][d], s_end[d][c][n].
__global__ void scan_a_kernel(const float* __restrict__ u,
                              const float* __restrict__ dt,
                              const float* __restrict__ xdbl,
                              const float* __restrict__ A_log,
                              float* __restrict__ yloc,     // stride 4096 (xz xp half)
                              float* __restrict__ cumdt,    // [l][d]
                              float* __restrict__ s_end) {  // [d][c][n]
    const int idx = blockIdx.x * 256 + threadIdx.x;   // 32768
    const int d = idx & 2047;
    const int c = idx >> 11;

    float Aa[16];
    #pragma unroll
    for (int q = 0; q < 4; ++q) {
        float4 al = *(const float4*)(A_log + (size_t)d * 16 + q * 4);
        Aa[q * 4 + 0] = -__expf(al.x);
        Aa[q * 4 + 1] = -__expf(al.y);
        Aa[q * 4 + 2] = -__expf(al.z);
        Aa[q * 4 + 3] = -__expf(al.w);
    }

    float s[16];
    #pragma unroll
    for (int n = 0; n < 16; ++n) s[n] = 0.0f;
    float cd = 0.0f;

    const int l0 = c * CLEN;
    for (int i = 0; i < CLEN; ++i) {
        const int l = l0 + i;
        const float dtl = dt[(size_t)l * 2048 + d];
        const float ul  = u[(size_t)l * 2048 + d];
        float Bn[16], Cn[16];
        const float* xbp = xdbl + (size_t)l * 96;
        *(float4*)&Bn[0]  = *(const float4*)(xbp + 64);
        *(float4*)&Bn[4]  = *(const float4*)(xbp + 68);
        *(float4*)&Bn[8]  = *(const float4*)(xbp + 72);
        *(float4*)&Bn[12] = *(const float4*)(xbp + 76);
        *(float4*)&Cn[0]  = *(const float4*)(xbp + 80);
        *(float4*)&Cn[4]  = *(const float4*)(xbp + 84);
        *(float4*)&Cn[8]  = *(const float4*)(xbp + 88);
        *(float4*)&Cn[12] = *(const float4*)(xbp + 92);
        cd += dtl;
        const float dtu = dtl * ul;
        float y = 0.0f;
        #pragma unroll
        for (int n = 0; n < 16; ++n) {
            float dA = __expf(dtl * Aa[n]);
            s[n] = fmaf(s[n], dA, dtu * Bn[n]);
            y = fmaf(s[n], Cn[n], y);
        }
        yloc[(size_t)l * 4096 + d] = y;
        cumdt[(size_t)l * 2048 + d] = cd;
    }
    float* se = s_end + ((size_t)d * NCHUNK + c) * 16;
    #pragma unroll
    for (int q = 0; q < 4; ++q)
        *(float4*)(se + q * 4) = make_float4(s[q * 4], s[q * 4 + 1], s[q * 4 + 2], s[q * 4 + 3]);
}

// Pass B: thread per (d,n). Sequential over chunks: entry states s_in[d][c][n].
__global__ void scan_b_kernel(const float* __restrict__ s_end,
                              const float* __restrict__ cumdt,
                              const float* __restrict__ A_log,
                              float* __restrict__ s_in) {
    const int idx = blockIdx.x * 256 + threadIdx.x;   // 32768
    const int d = idx >> 4;
    const int n = idx & 15;
    const float Aa = -__expf(A_log[(size_t)d * 16 + n]);
    float s = 0.0f;
    #pragma unroll
    for (int c = 0; c < NCHUNK; ++c) {
        s_in[((size_t)d * NCHUNK + c) * 16 + n] = s;
        const float tot = cumdt[(size_t)(c * CLEN + CLEN - 1) * 2048 + d];
        s = s_end[((size_t)d * NCHUNK + c) * 16 + n] + __expf(Aa * tot) * s;
    }
}

// Pass C: thread per (l,d). y = (yloc + sum_n C_n*exp(A_n*cumdt)*s_in_n + D*u) * silu(z)
__global__ void scan_c_kernel(const float* __restrict__ u,
                              const float* __restrict__ xdbl,
                              const float* __restrict__ A_log,
                              const float* __restrict__ Dv,
                              const float* __restrict__ xz,   // yloc in xp half, z in z half
                              const float* __restrict__ cumdt,
                              const float* __restrict__ s_in,
                              ushort* __restrict__ yb) {
    const int idx = blockIdx.x * 256 + threadIdx.x;   // l*2048+d
    const int l = idx >> 11;
    const int d = idx & 2047;
    const int c = l >> 6;   // CLEN=64

    const float cd = cumdt[idx];
    const float ul = u[idx];
    const float yv = xz[(size_t)l * 4096 + d];
    const float zv = xz[(size_t)l * 4096 + 2048 + d];
    const float* Cp = xdbl + (size_t)l * 96 + 80;
    const float* si = s_in + ((size_t)d * NCHUNK + c) * 16;

    float corr = 0.0f;
    #pragma unroll
    for (int q = 0; q < 4; ++q) {
        float4 al = *(const float4*)(A_log + (size_t)d * 16 + q * 4);
        float4 cv = *(const float4*)(Cp + q * 4);
        float4 sv = *(const float4*)(si + q * 4);
        corr = fmaf(cv.x * __expf(-__expf(al.x) * cd), sv.x, corr);
        corr = fmaf(cv.y * __expf(-__expf(al.y) * cd), sv.y, corr);
        corr = fmaf(cv.z * __expf(-__expf(al.z) * cd), sv.z, corr);
        corr = fmaf(cv.w * __expf(-__expf(al.w) * cd), sv.w, corr);
    }
    const float y = (yv + corr + Dv[d] * ul) * silu_f(zv);
    yb[idx] = f2bf(y);
}

extern "C" void kernel_launch(void* const* d_in, const int* in_sizes, int n_in,
                              void* d_out, int out_size, void* d_ws, size_t ws_size,
                              hipStream_t stream) {
    const int*   ids        = (const int*)d_in[0];
    const float* emb        = (const float*)d_in[1];
    const float* norm_w     = (const float*)d_in[2];
    const float* in_proj_w  = (const float*)d_in[3];
    const float* conv_w     = (const float*)d_in[4];
    const float* conv_b     = (const float*)d_in[5];
    const float* x_proj_w   = (const float*)d_in[6];
    const float* dt_proj_w  = (const float*)d_in[7];
    const float* dt_proj_b  = (const float*)d_in[8];
    const float* A_log      = (const float*)d_in[9];
    const float* Dv         = (const float*)d_in[10];
    const float* out_proj_w = (const float*)d_in[11];
    const float* norm_f_w   = (const float*)d_in[12];
    float* out = (float*)d_out;

    // ---- workspace layout ----
    char* p = (char*)d_ws;
    ushort* emb_b  = (ushort*)p; p += (size_t)VOCAB * D_MODEL * 2;
    ushort* inw_b  = (ushort*)p; p += (size_t)N_LAYER * 4096 * 1024 * 2;
    ushort* outw_b = (ushort*)p; p += (size_t)N_LAYER * 1024 * 2048 * 2;
    ushort* xpw_b  = (ushort*)p; p += (size_t)N_LAYER * 96 * 2048 * 2;
    float* residual = (float*)p; p += (size_t)SEQ_L * D_MODEL * 4;
    float* hidden   = (float*)p; p += (size_t)SEQ_L * D_MODEL * 4;
    ushort* xb      = (ushort*)p; p += (size_t)SEQ_L * D_MODEL * 2;
    float* xz       = (float*)p; p += (size_t)SEQ_L * 4096 * 4;
    float* u        = (float*)p; p += (size_t)SEQ_L * 2048 * 4;
    ushort* u_b     = (ushort*)p; p += (size_t)SEQ_L * 2048 * 2;
    float* dtb      = (float*)p; p += (size_t)SEQ_L * 2048 * 4;
    float* xdbl     = (float*)p; p += (size_t)SEQ_L * 96 * 4;
    ushort* yb      = (ushort*)p; p += (size_t)SEQ_L * 2048 * 2;
    float* cumdt    = (float*)p; p += (size_t)SEQ_L * 2048 * 4;           // 8.4 MB
    float* s_end    = (float*)p; p += (size_t)D_INNER * NCHUNK * 16 * 4;  // 2.1 MB
    float* s_in     = (float*)p; p += (size_t)D_INNER * NCHUNK * 16 * 4;  // 2.1 MB

    dim3 blk(256);

    f32_to_bf16_kernel<<<dim3(VOCAB * D_MODEL / 4 / 256), blk, 0, stream>>>(
        emb, emb_b, VOCAB * D_MODEL / 4);
    f32_to_bf16_kernel<<<dim3(N_LAYER * 4096 * 1024 / 4 / 256), blk, 0, stream>>>(
        in_proj_w, inw_b, N_LAYER * 4096 * 1024 / 4);
    f32_to_bf16_kernel<<<dim3(N_LAYER * 1024 * 2048 / 4 / 256), blk, 0, stream>>>(
        out_proj_w, outw_b, N_LAYER * 1024 * 2048 / 4);
    f32_to_bf16_kernel<<<dim3(N_LAYER * 96 * 2048 / 4 / 256), blk, 0, stream>>>(
        x_proj_w, xpw_b, N_LAYER * 96 * 2048 / 4);

    embed_kernel<<<dim3(SEQ_L), blk, 0, stream>>>(ids, emb, hidden);

    for (int i = 0; i < N_LAYER; ++i) {
        add_rmsnorm_kernel<<<dim3(SEQ_L), blk, 0, stream>>>(
            residual, hidden, norm_w + (size_t)i * D_MODEL, xb, i == 0 ? 0 : 1);

        // xz = x @ in_proj^T : M=1024 N=4096 K=1024
        gemm_bf16_mfma_kernel<0><<<dim3(32, 8, 1), blk, 0, stream>>>(
            xb, inw_b + (size_t)i * 4096 * 1024, xz, 4096, 1024, 1024, 4096, 1024);

        conv_silu_kernel<<<dim3(SEQ_L * D_INNER / 256), blk, 0, stream>>>(
            xz, conv_w + (size_t)i * D_INNER * D_CONV, conv_b + (size_t)i * D_INNER,
            u, u_b);

        // xdbl = u @ x_proj^T : M=1024 N=96 K=2048, split-K 8-way
        zero_kernel<<<dim3(SEQ_L * 96 / 4 / 256), blk, 0, stream>>>(xdbl, SEQ_L * 96 / 4);
        gemm_bf16_mfma_kernel<1><<<dim3(1, 8, 8), blk, 0, stream>>>(
            u_b, xpw_b + (size_t)i * 96 * 2048, xdbl, 96, 2048, 2048, 96, 256);

        // dt = softplus(dt_r @ dt_proj^T + b)
        gemm_tn_kernel<1><<<dim3(D_INNER / 64, SEQ_L / 64), blk, 0, stream>>>(
            xdbl, dt_proj_w + (size_t)i * D_INNER * DT_RANK,
            dt_proj_b + (size_t)i * D_INNER, dtb,
            SEQ_L, D_INNER, DT_RANK, 96);

        // chunked scan
        scan_a_kernel<<<dim3(D_INNER * NCHUNK / 256), blk, 0, stream>>>(
            u, dtb, xdbl, A_log + (size_t)i * D_INNER * D_STATE, xz, cumdt, s_end);
        scan_b_kernel<<<dim3(D_INNER * 16 / 256), blk, 0, stream>>>(
            s_end, cumdt, A_log + (size_t)i * D_INNER * D_STATE, s_in);
        scan_c_kernel<<<dim3(SEQ_L * D_INNER / 256), blk, 0, stream>>>(
            u, xdbl, A_log + (size_t)i * D_INNER * D_STATE,
            Dv + (size_t)i * D_INNER, xz, cumdt, s_in, yb);

        // hidden = y @ out_proj^T : M=1024 N=1024 K=2048
        gemm_bf16_mfma_kernel<0><<<dim3(8, 8, 1), blk, 0, stream>>>(
            yb, outw_b + (size_t)i * 1024 * 2048, hidden, 1024, 2048, 2048, 1024, 2048);
    }

    add_rmsnorm_kernel<<<dim3(SEQ_L), blk, 0, stream>>>(
        residual, hidden, norm_f_w, xb, 1);

    // logits = hf @ emb^T : M=1024 N=50280 K=1024
    gemm_bf16_mfma_kernel<0><<<dim3((VOCAB + 127) / 128, 8, 1), blk, 0, stream>>>(
        xb, emb_b, out, VOCAB, 1024, 1024, VOCAB, 1024);
}

// Round 4
// 1002.728 us; speedup vs baseline: 5.0051x; 1.0358x over previous
//
#include <hip/hip_runtime.h>
#include <hip/hip_bf16.h>

#define D_MODEL 1024
#define N_LAYER 4
#define D_INNER 2048
#define D_STATE 16
#define D_CONV  4
#define DT_RANK 64
#define SEQ_L   1024
#define VOCAB   50280
#define NCHUNK  32
#define CLEN    32

typedef __attribute__((ext_vector_type(8))) short short8;
typedef __attribute__((ext_vector_type(4))) float f32x4;

__device__ __forceinline__ float silu_f(float x) {
    return x / (1.0f + __expf(-x));
}
__device__ __forceinline__ float softplus_f(float x) {
    return fmaxf(x, 0.0f) + log1pf(__expf(-fabsf(x)));
}
__device__ __forceinline__ ushort f2bf(float f) {
    union { float f; unsigned u; } uf; uf.f = f;
    unsigned r = uf.u + 0x7FFF + ((uf.u >> 16) & 1);   // RNE
    return (ushort)(r >> 16);
}
__device__ __forceinline__ short8 pack8(const float4& a, const float4& b) {
    short8 r;
    r[0] = (short)f2bf(a.x); r[1] = (short)f2bf(a.y);
    r[2] = (short)f2bf(a.z); r[3] = (short)f2bf(a.w);
    r[4] = (short)f2bf(b.x); r[5] = (short)f2bf(b.y);
    r[6] = (short)f2bf(b.z); r[7] = (short)f2bf(b.w);
    return r;
}

// ---------------- fp32 -> bf16 bulk convert (embedding only) ----------------
__global__ void f32_to_bf16_kernel(const float* __restrict__ in,
                                   ushort* __restrict__ out, int n4) {
    int i = blockIdx.x * 256 + threadIdx.x;
    if (i >= n4) return;
    float4 v = *(const float4*)(in + (size_t)i * 4);
    ushort4 o;
    o.x = f2bf(v.x); o.y = f2bf(v.y); o.z = f2bf(v.z); o.w = f2bf(v.w);
    *(ushort4*)(out + (size_t)i * 4) = o;
}

__global__ void zero_kernel(float* __restrict__ p, int n4) {
    int i = blockIdx.x * 256 + threadIdx.x;
    if (i < n4) *(float4*)(p + (size_t)i * 4) = make_float4(0.f, 0.f, 0.f, 0.f);
}

// ---------------- embedding gather ----------------
__global__ void embed_kernel(const int* __restrict__ ids,
                             const float* __restrict__ emb,
                             float* __restrict__ hidden) {
    int l = blockIdx.x;
    int t = threadIdx.x;
    int id = ids[l];
    float4 v = *(const float4*)(emb + (size_t)id * D_MODEL + t * 4);
    *(float4*)(hidden + (size_t)l * D_MODEL + t * 4) = v;
}

// ---------------- residual add + RMSNorm -> bf16 x ----------------
__global__ void add_rmsnorm_kernel(float* __restrict__ res,
                                   const float* __restrict__ h,
                                   const float* __restrict__ w,
                                   ushort* __restrict__ xout,
                                   int add) {
    int l = blockIdx.x;
    int t = threadIdx.x;
    size_t base = (size_t)l * D_MODEL + t * 4;
    float4 hv = *(const float4*)(h + base);
    float4 r;
    if (add) {
        r = *(const float4*)(res + base);
        r.x += hv.x; r.y += hv.y; r.z += hv.z; r.w += hv.w;
    } else {
        r = hv;
    }
    *(float4*)(res + base) = r;
    float ss = r.x * r.x + r.y * r.y + r.z * r.z + r.w * r.w;
    #pragma unroll
    for (int off = 32; off > 0; off >>= 1) ss += __shfl_down(ss, off, 64);
    __shared__ float sred[4];
    if ((t & 63) == 0) sred[t >> 6] = ss;
    __syncthreads();
    float tot = sred[0] + sred[1] + sred[2] + sred[3];
    float scale = rsqrtf(tot * (1.0f / (float)D_MODEL) + 1e-5f);
    float4 wv = *(const float4*)(w + t * 4);
    ushort4 o;
    o.x = f2bf(r.x * scale * wv.x);
    o.y = f2bf(r.y * scale * wv.y);
    o.z = f2bf(r.z * scale * wv.z);
    o.w = f2bf(r.w * scale * wv.w);
    *(ushort4*)(xout + base) = o;
}

// ---------------- bf16 MFMA TN GEMM ----------------
// Linear grid, XCD-banded decode: j=(id%8)*T+id/8; (n,m,ks) with ks,m fastest.
// Each XCD gets a contiguous band of n-panels; all M-tiles (and K-splits) of a
// panel run consecutively on that XCD -> weight panel stays hot in its L2.
// WF32: weight is fp32 in global, converted to bf16 during LDS staging.
// ATOMIC: atomicAdd epilogue (C pre-zeroed) for split-K.
// Requires gridDim.x == NB*MB*KS, divisible by 8; M%128==0; (K/KS)%32==0.
template<int ATOMIC, int WF32>
__global__ __launch_bounds__(256)
void gemm_bf16_mfma_kernel(const ushort* __restrict__ A,
                           const void* __restrict__ Wv,
                           float* __restrict__ C,
                           int N, int K, int lda, int ldc,
                           int MB, int KS) {
    __shared__ ushort As[128][40];
    __shared__ ushort Ws[128][40];
    const int t  = threadIdx.x;
    const int T  = gridDim.x >> 3;
    const int id = blockIdx.x;
    const int j  = (id & 7) * T + (id >> 3);
    const int ks  = j % KS;
    const int rem = j / KS;
    const int m0 = (rem % MB) * 128;
    const int n0 = (rem / MB) * 128;
    const int kchunk = K / KS;
    const int kbeg = ks * kchunk;
    const int kend = kbeg + kchunk;

    const int srow = t >> 1;
    const int skc  = (t & 1) * 16;
    const ushort* Ag = A + (size_t)(m0 + srow) * lda + skc;
    const bool wvld = (n0 + srow) < N;
    const ushort* Wg   = (const ushort*)Wv + (size_t)(wvld ? (n0 + srow) : 0) * K + skc;
    const float*  Wg32 = (const float*)Wv  + (size_t)(wvld ? (n0 + srow) : 0) * K + skc;

    const int lane = t & 63;
    const int wm = (t >> 7) & 1;
    const int wn = (t >> 6) & 1;
    const int lr = lane & 15;
    const int lk = lane >> 4;

    f32x4 acc[4][4] = {};
    const short8 zero8 = {0, 0, 0, 0, 0, 0, 0, 0};
    const float4 zf4 = make_float4(0.f, 0.f, 0.f, 0.f);

    short8 a0 = *(const short8*)(Ag + kbeg);
    short8 a1 = *(const short8*)(Ag + kbeg + 8);
    short8 w0, w1;
    float4 wf0, wf1, wf2, wf3;
    if constexpr (WF32) {
        wf0 = wvld ? *(const float4*)(Wg32 + kbeg)      : zf4;
        wf1 = wvld ? *(const float4*)(Wg32 + kbeg + 4)  : zf4;
        wf2 = wvld ? *(const float4*)(Wg32 + kbeg + 8)  : zf4;
        wf3 = wvld ? *(const float4*)(Wg32 + kbeg + 12) : zf4;
    } else {
        w0 = wvld ? *(const short8*)(Wg + kbeg)     : zero8;
        w1 = wvld ? *(const short8*)(Wg + kbeg + 8) : zero8;
    }

    for (int k0 = kbeg;;) {
        *(short8*)&As[srow][skc]     = a0;
        *(short8*)&As[srow][skc + 8] = a1;
        if constexpr (WF32) {
            *(short8*)&Ws[srow][skc]     = pack8(wf0, wf1);
            *(short8*)&Ws[srow][skc + 8] = pack8(wf2, wf3);
        } else {
            *(short8*)&Ws[srow][skc]     = w0;
            *(short8*)&Ws[srow][skc + 8] = w1;
        }
        __syncthreads();

        k0 += 32;
        const bool more = k0 < kend;
        if (more) {
            a0 = *(const short8*)(Ag + k0);
            a1 = *(const short8*)(Ag + k0 + 8);
            if (wvld) {
                if constexpr (WF32) {
                    wf0 = *(const float4*)(Wg32 + k0);
                    wf1 = *(const float4*)(Wg32 + k0 + 4);
                    wf2 = *(const float4*)(Wg32 + k0 + 8);
                    wf3 = *(const float4*)(Wg32 + k0 + 12);
                } else {
                    w0 = *(const short8*)(Wg + k0);
                    w1 = *(const short8*)(Wg + k0 + 8);
                }
            }
        }

        short8 af[4], bfr[4];
        #pragma unroll
        for (int m = 0; m < 4; ++m)
            af[m] = *(const short8*)&As[wm * 64 + m * 16 + lr][lk * 8];
        #pragma unroll
        for (int n = 0; n < 4; ++n)
            bfr[n] = *(const short8*)&Ws[wn * 64 + n * 16 + lr][lk * 8];
        #pragma unroll
        for (int m = 0; m < 4; ++m)
            #pragma unroll
            for (int n = 0; n < 4; ++n)
                acc[m][n] = __builtin_amdgcn_mfma_f32_16x16x32_bf16(
                    af[m], bfr[n], acc[m][n], 0, 0, 0);

        if (!more) break;
        __syncthreads();
    }

    #pragma unroll
    for (int m = 0; m < 4; ++m) {
        const int row = m0 + wm * 64 + m * 16 + lk * 4;
        #pragma unroll
        for (int n = 0; n < 4; ++n) {
            const int col = n0 + wn * 64 + n * 16 + lr;
            if (col < N) {
                #pragma unroll
                for (int r = 0; r < 4; ++r) {
                    if (ATOMIC)
                        atomicAdd(&C[(size_t)(row + r) * ldc + col], acc[m][n][r]);
                    else
                        C[(size_t)(row + r) * ldc + col] = acc[m][n][r];
                }
            }
        }
    }
}

// ---------------- fp32 TN GEMM (dt_proj only) ----------------
template<int EPI>
__global__ void gemm_tn_kernel(const float* __restrict__ A,
                               const float* __restrict__ W,
                               const float* __restrict__ bias,
                               float* __restrict__ C,
                               int M, int N, int K, int lda) {
    __shared__ float As[16][68];
    __shared__ float Ws[16][68];
    const int t  = threadIdx.x;
    const int m0 = blockIdx.y * 64;
    const int n0 = blockIdx.x * 64;
    const int lrow = t >> 2;
    const int lkq  = (t & 3) * 4;
    const int tx = t & 15;
    const int ty = t >> 4;

    const float* Arow = A + (size_t)(m0 + lrow) * lda;
    const int   wr    = n0 + lrow;
    const bool  wvalid = wr < N;
    const float* Wrow = W + (size_t)(wvalid ? wr : 0) * K;

    float acc[4][4] = {};
    for (int k0 = 0; k0 < K; k0 += 16) {
        float4 av = *(const float4*)(Arow + k0 + lkq);
        float4 wv = wvalid ? *(const float4*)(Wrow + k0 + lkq)
                           : make_float4(0.f, 0.f, 0.f, 0.f);
        As[lkq + 0][lrow] = av.x; As[lkq + 1][lrow] = av.y;
        As[lkq + 2][lrow] = av.z; As[lkq + 3][lrow] = av.w;
        Ws[lkq + 0][lrow] = wv.x; Ws[lkq + 1][lrow] = wv.y;
        Ws[lkq + 2][lrow] = wv.z; Ws[lkq + 3][lrow] = wv.w;
        __syncthreads();
        #pragma unroll
        for (int kk = 0; kk < 16; ++kk) {
            float4 a = *(const float4*)&As[kk][ty * 4];
            float4 b = *(const float4*)&Ws[kk][tx * 4];
            #pragma unroll
            for (int i = 0; i < 4; ++i) {
                float ai = (i == 0) ? a.x : (i == 1) ? a.y : (i == 2) ? a.z : a.w;
                acc[i][0] = fmaf(ai, b.x, acc[i][0]);
                acc[i][1] = fmaf(ai, b.y, acc[i][1]);
                acc[i][2] = fmaf(ai, b.z, acc[i][2]);
                acc[i][3] = fmaf(ai, b.w, acc[i][3]);
            }
        }
        __syncthreads();
    }

    const int colb = n0 + tx * 4;
    if (colb < N) {
        #pragma unroll
        for (int i = 0; i < 4; ++i) {
            int row = m0 + ty * 4 + i;
            float4 v = make_float4(acc[i][0], acc[i][1], acc[i][2], acc[i][3]);
            if (EPI == 1) {
                v.x = softplus_f(v.x + bias[colb + 0]);
                v.y = softplus_f(v.y + bias[colb + 1]);
                v.z = softplus_f(v.z + bias[colb + 2]);
                v.w = softplus_f(v.w + bias[colb + 3]);
            }
            *(float4*)(C + (size_t)row * N + colb) = v;
        }
    }
}

// ---------------- depthwise causal conv (k=4) + silu ----------------
__global__ void conv_silu_kernel(const float* __restrict__ xz,
                                 const float* __restrict__ cw,
                                 const float* __restrict__ cb,
                                 float* __restrict__ u,
                                 ushort* __restrict__ u_b) {
    int idx = blockIdx.x * 256 + threadIdx.x;
    int l = idx >> 11;
    int c = idx & 2047;
    float acc = cb[c];
    float w0 = cw[c * 4 + 0], w1 = cw[c * 4 + 1], w2 = cw[c * 4 + 2], w3 = cw[c * 4 + 3];
    if (l >= 3) acc = fmaf(xz[(size_t)(l - 3) * 4096 + c], w0, acc);
    if (l >= 2) acc = fmaf(xz[(size_t)(l - 2) * 4096 + c], w1, acc);
    if (l >= 1) acc = fmaf(xz[(size_t)(l - 1) * 4096 + c], w2, acc);
    acc = fmaf(xz[(size_t)l * 4096 + c], w3, acc);
    float s = silu_f(acc);
    u[idx] = s;
    u_b[idx] = f2bf(s);
}

// ---------------- chunked selective scan ----------------
__global__ void scan_a_kernel(const float* __restrict__ u,
                              const float* __restrict__ dt,
                              const float* __restrict__ xdbl,
                              const float* __restrict__ A_log,
                              float* __restrict__ yloc,     // stride 4096 (xz xp half)
                              float* __restrict__ cumdt,    // [l][d]
                              float* __restrict__ s_end) {  // [d][c][n]
    const int idx = blockIdx.x * 256 + threadIdx.x;   // 65536
    const int d = idx & 2047;
    const int c = idx >> 11;

    float Aa[16];
    #pragma unroll
    for (int q = 0; q < 4; ++q) {
        float4 al = *(const float4*)(A_log + (size_t)d * 16 + q * 4);
        Aa[q * 4 + 0] = -__expf(al.x);
        Aa[q * 4 + 1] = -__expf(al.y);
        Aa[q * 4 + 2] = -__expf(al.z);
        Aa[q * 4 + 3] = -__expf(al.w);
    }

    float s[16];
    #pragma unroll
    for (int n = 0; n < 16; ++n) s[n] = 0.0f;
    float cd = 0.0f;

    const int l0 = c * CLEN;
    for (int i = 0; i < CLEN; ++i) {
        const int l = l0 + i;
        const float dtl = dt[(size_t)l * 2048 + d];
        const float ul  = u[(size_t)l * 2048 + d];
        float Bn[16], Cn[16];
        const float* xbp = xdbl + (size_t)l * 96;
        *(float4*)&Bn[0]  = *(const float4*)(xbp + 64);
        *(float4*)&Bn[4]  = *(const float4*)(xbp + 68);
        *(float4*)&Bn[8]  = *(const float4*)(xbp + 72);
        *(float4*)&Bn[12] = *(const float4*)(xbp + 76);
        *(float4*)&Cn[0]  = *(const float4*)(xbp + 80);
        *(float4*)&Cn[4]  = *(const float4*)(xbp + 84);
        *(float4*)&Cn[8]  = *(const float4*)(xbp + 88);
        *(float4*)&Cn[12] = *(const float4*)(xbp + 92);
        cd += dtl;
        const float dtu = dtl * ul;
        float y = 0.0f;
        #pragma unroll
        for (int n = 0; n < 16; ++n) {
            float dA = __expf(dtl * Aa[n]);
            s[n] = fmaf(s[n], dA, dtu * Bn[n]);
            y = fmaf(s[n], Cn[n], y);
        }
        yloc[(size_t)l * 4096 + d] = y;
        cumdt[(size_t)l * 2048 + d] = cd;
    }
    float* se = s_end + ((size_t)d * NCHUNK + c) * 16;
    #pragma unroll
    for (int q = 0; q < 4; ++q)
        *(float4*)(se + q * 4) = make_float4(s[q * 4], s[q * 4 + 1], s[q * 4 + 2], s[q * 4 + 3]);
}

__global__ void scan_b_kernel(const float* __restrict__ s_end,
                              const float* __restrict__ cumdt,
                              const float* __restrict__ A_log,
                              float* __restrict__ s_in) {
    const int idx = blockIdx.x * 256 + threadIdx.x;   // 32768
    const int d = idx >> 4;
    const int n = idx & 15;
    const float Aa = -__expf(A_log[(size_t)d * 16 + n]);
    float s = 0.0f;
    #pragma unroll
    for (int c = 0; c < NCHUNK; ++c) {
        s_in[((size_t)d * NCHUNK + c) * 16 + n] = s;
        const float tot = cumdt[(size_t)(c * CLEN + CLEN - 1) * 2048 + d];
        s = s_end[((size_t)d * NCHUNK + c) * 16 + n] + __expf(Aa * tot) * s;
    }
}

__global__ void scan_c_kernel(const float* __restrict__ u,
                              const float* __restrict__ xdbl,
                              const float* __restrict__ A_log,
                              const float* __restrict__ Dv,
                              const float* __restrict__ xz,
                              const float* __restrict__ cumdt,
                              const float* __restrict__ s_in,
                              ushort* __restrict__ yb) {
    const int idx = blockIdx.x * 256 + threadIdx.x;   // l*2048+d
    const int l = idx >> 11;
    const int d = idx & 2047;
    const int c = l >> 5;   // CLEN=32

    const float cd = cumdt[idx];
    const float ul = u[idx];
    const float yv = xz[(size_t)l * 4096 + d];
    const float zv = xz[(size_t)l * 4096 + 2048 + d];
    const float* Cp = xdbl + (size_t)l * 96 + 80;
    const float* si = s_in + ((size_t)d * NCHUNK + c) * 16;

    float corr = 0.0f;
    #pragma unroll
    for (int q = 0; q < 4; ++q) {
        float4 al = *(const float4*)(A_log + (size_t)d * 16 + q * 4);
        float4 cv = *(const float4*)(Cp + q * 4);
        float4 sv = *(const float4*)(si + q * 4);
        corr = fmaf(cv.x * __expf(-__expf(al.x) * cd), sv.x, corr);
        corr = fmaf(cv.y * __expf(-__expf(al.y) * cd), sv.y, corr);
        corr = fmaf(cv.z * __expf(-__expf(al.z) * cd), sv.z, corr);
        corr = fmaf(cv.w * __expf(-__expf(al.w) * cd), sv.w, corr);
    }
    const float y = (yv + corr + Dv[d] * ul) * silu_f(zv);
    yb[idx] = f2bf(y);
}

extern "C" void kernel_launch(void* const* d_in, const int* in_sizes, int n_in,
                              void* d_out, int out_size, void* d_ws, size_t ws_size,
                              hipStream_t stream) {
    const int*   ids        = (const int*)d_in[0];
    const float* emb        = (const float*)d_in[1];
    const float* norm_w     = (const float*)d_in[2];
    const float* in_proj_w  = (const float*)d_in[3];
    const float* conv_w     = (const float*)d_in[4];
    const float* conv_b     = (const float*)d_in[5];
    const float* x_proj_w   = (const float*)d_in[6];
    const float* dt_proj_w  = (const float*)d_in[7];
    const float* dt_proj_b  = (const float*)d_in[8];
    const float* A_log      = (const float*)d_in[9];
    const float* Dv         = (const float*)d_in[10];
    const float* out_proj_w = (const float*)d_in[11];
    const float* norm_f_w   = (const float*)d_in[12];
    float* out = (float*)d_out;

    // ---- workspace layout ----
    char* p = (char*)d_ws;
    ushort* emb_b  = (ushort*)p; p += (size_t)VOCAB * D_MODEL * 2;        // 103 MB
    float* residual = (float*)p; p += (size_t)SEQ_L * D_MODEL * 4;
    float* hidden   = (float*)p; p += (size_t)SEQ_L * D_MODEL * 4;
    ushort* xb      = (ushort*)p; p += (size_t)SEQ_L * D_MODEL * 2;
    float* xz       = (float*)p; p += (size_t)SEQ_L * 4096 * 4;
    float* u        = (float*)p; p += (size_t)SEQ_L * 2048 * 4;
    ushort* u_b     = (ushort*)p; p += (size_t)SEQ_L * 2048 * 2;
    float* dtb      = (float*)p; p += (size_t)SEQ_L * 2048 * 4;
    float* xdbl     = (float*)p; p += (size_t)SEQ_L * 96 * 4;
    ushort* yb      = (ushort*)p; p += (size_t)SEQ_L * 2048 * 2;
    float* cumdt    = (float*)p; p += (size_t)SEQ_L * 2048 * 4;
    float* s_end    = (float*)p; p += (size_t)D_INNER * NCHUNK * 16 * 4;  // 4.2 MB
    float* s_in     = (float*)p; p += (size_t)D_INNER * NCHUNK * 16 * 4;  // 4.2 MB

    dim3 blk(256);

    // embedding -> bf16 (LM-head weight; halves its HBM stream)
    f32_to_bf16_kernel<<<dim3(VOCAB * D_MODEL / 4 / 256), blk, 0, stream>>>(
        emb, emb_b, VOCAB * D_MODEL / 4);

    embed_kernel<<<dim3(SEQ_L), blk, 0, stream>>>(ids, emb, hidden);

    for (int i = 0; i < N_LAYER; ++i) {
        add_rmsnorm_kernel<<<dim3(SEQ_L), blk, 0, stream>>>(
            residual, hidden, norm_w + (size_t)i * D_MODEL, xb, i == 0 ? 0 : 1);

        // xz = x @ in_proj^T : M=1024 N=4096 K=1024  (NB=32, MB=8, KS=1 -> 256 blocks)
        gemm_bf16_mfma_kernel<0, 1><<<dim3(256), blk, 0, stream>>>(
            xb, in_proj_w + (size_t)i * 4096 * 1024, xz, 4096, 1024, 1024, 4096, 8, 1);

        conv_silu_kernel<<<dim3(SEQ_L * D_INNER / 256), blk, 0, stream>>>(
            xz, conv_w + (size_t)i * D_INNER * D_CONV, conv_b + (size_t)i * D_INNER,
            u, u_b);

        // xdbl = u @ x_proj^T : M=1024 N=96 K=2048  (NB=1, MB=8, KS=16 -> 128 blocks)
        zero_kernel<<<dim3(SEQ_L * 96 / 4 / 256), blk, 0, stream>>>(xdbl, SEQ_L * 96 / 4);
        gemm_bf16_mfma_kernel<1, 1><<<dim3(128), blk, 0, stream>>>(
            u_b, x_proj_w + (size_t)i * 96 * 2048, xdbl, 96, 2048, 2048, 96, 8, 16);

        // dt = softplus(dt_r @ dt_proj^T + b)
        gemm_tn_kernel<1><<<dim3(D_INNER / 64, SEQ_L / 64), blk, 0, stream>>>(
            xdbl, dt_proj_w + (size_t)i * D_INNER * DT_RANK,
            dt_proj_b + (size_t)i * D_INNER, dtb,
            SEQ_L, D_INNER, DT_RANK, 96);

        // chunked scan
        scan_a_kernel<<<dim3(D_INNER * NCHUNK / 256), blk, 0, stream>>>(
            u, dtb, xdbl, A_log + (size_t)i * D_INNER * D_STATE, xz, cumdt, s_end);
        scan_b_kernel<<<dim3(D_INNER * 16 / 256), blk, 0, stream>>>(
            s_end, cumdt, A_log + (size_t)i * D_INNER * D_STATE, s_in);
        scan_c_kernel<<<dim3(SEQ_L * D_INNER / 256), blk, 0, stream>>>(
            u, xdbl, A_log + (size_t)i * D_INNER * D_STATE,
            Dv + (size_t)i * D_INNER, xz, cumdt, s_in, yb);

        // hidden = y @ out_proj^T : M=1024 N=1024 K=2048 (NB=8, MB=8, KS=4 -> 256 blocks)
        zero_kernel<<<dim3(SEQ_L * D_MODEL / 4 / 256), blk, 0, stream>>>(
            hidden, SEQ_L * D_MODEL / 4);
        gemm_bf16_mfma_kernel<1, 1><<<dim3(256), blk, 0, stream>>>(
            yb, out_proj_w + (size_t)i * 1024 * 2048, hidden, 1024, 2048, 2048, 1024, 8, 4);
    }

    add_rmsnorm_kernel<<<dim3(SEQ_L), blk, 0, stream>>>(
        residual, hidden, norm_f_w, xb, 1);

    // logits = hf @ emb^T : M=1024 N=50280 K=1024 (NB=393, MB=8, KS=1 -> 3144 blocks)
    gemm_bf16_mfma_kernel<0, 0><<<dim3(3144), blk, 0, stream>>>(
        xb, emb_b, out, VOCAB, 1024, 1024, VOCAB, 8, 1);
}

// Round 5
// 916.017 us; speedup vs baseline: 5.4789x; 1.0947x over previous
//
#include <hip/hip_runtime.h>
#include <hip/hip_bf16.h>

#define D_MODEL 1024
#define N_LAYER 4
#define D_INNER 2048
#define D_STATE 16
#define D_CONV  4
#define DT_RANK 64
#define SEQ_L   1024
#define VOCAB   50280
#define VOCAB_PAD 50304   // 393*128
#define NCHUNK  32
#define CLEN    32

typedef __attribute__((ext_vector_type(8))) short short8;
typedef __attribute__((ext_vector_type(4))) float f32x4;

typedef __attribute__((address_space(1))) const unsigned GUint;
typedef __attribute__((address_space(3))) unsigned LUint;

__device__ __forceinline__ float silu_f(float x) {
    return x / (1.0f + __expf(-x));
}
__device__ __forceinline__ float softplus_f(float x) {
    return fmaxf(x, 0.0f) + log1pf(__expf(-fabsf(x)));
}
__device__ __forceinline__ ushort f2bf(float f) {
    union { float f; unsigned u; } uf; uf.f = f;
    unsigned r = uf.u + 0x7FFF + ((uf.u >> 16) & 1);   // RNE
    return (ushort)(r >> 16);
}
__device__ __forceinline__ short8 pack8(const float4& a, const float4& b) {
    short8 r;
    r[0] = (short)f2bf(a.x); r[1] = (short)f2bf(a.y);
    r[2] = (short)f2bf(a.z); r[3] = (short)f2bf(a.w);
    r[4] = (short)f2bf(b.x); r[5] = (short)f2bf(b.y);
    r[6] = (short)f2bf(b.z); r[7] = (short)f2bf(b.w);
    return r;
}

// ---------------- fp32 -> bf16 bulk convert (embedding only) ----------------
__global__ void f32_to_bf16_kernel(const float* __restrict__ in,
                                   ushort* __restrict__ out, int n4) {
    int i = blockIdx.x * 256 + threadIdx.x;
    if (i >= n4) return;
    float4 v = *(const float4*)(in + (size_t)i * 4);
    ushort4 o;
    o.x = f2bf(v.x); o.y = f2bf(v.y); o.z = f2bf(v.z); o.w = f2bf(v.w);
    *(ushort4*)(out + (size_t)i * 4) = o;
}

__global__ void zero_kernel(float* __restrict__ p, int n4) {
    int i = blockIdx.x * 256 + threadIdx.x;
    if (i < n4) *(float4*)(p + (size_t)i * 4) = make_float4(0.f, 0.f, 0.f, 0.f);
}

// ---------------- embedding gather ----------------
__global__ void embed_kernel(const int* __restrict__ ids,
                             const float* __restrict__ emb,
                             float* __restrict__ hidden) {
    int l = blockIdx.x;
    int t = threadIdx.x;
    int id = ids[l];
    float4 v = *(const float4*)(emb + (size_t)id * D_MODEL + t * 4);
    *(float4*)(hidden + (size_t)l * D_MODEL + t * 4) = v;
}

// ---------------- residual add + RMSNorm -> bf16 x ----------------
__global__ void add_rmsnorm_kernel(float* __restrict__ res,
                                   const float* __restrict__ h,
                                   const float* __restrict__ w,
                                   ushort* __restrict__ xout,
                                   int add) {
    int l = blockIdx.x;
    int t = threadIdx.x;
    size_t base = (size_t)l * D_MODEL + t * 4;
    float4 hv = *(const float4*)(h + base);
    float4 r;
    if (add) {
        r = *(const float4*)(res + base);
        r.x += hv.x; r.y += hv.y; r.z += hv.z; r.w += hv.w;
    } else {
        r = hv;
    }
    *(float4*)(res + base) = r;
    float ss = r.x * r.x + r.y * r.y + r.z * r.z + r.w * r.w;
    #pragma unroll
    for (int off = 32; off > 0; off >>= 1) ss += __shfl_down(ss, off, 64);
    __shared__ float sred[4];
    if ((t & 63) == 0) sred[t >> 6] = ss;
    __syncthreads();
    float tot = sred[0] + sred[1] + sred[2] + sred[3];
    float scale = rsqrtf(tot * (1.0f / (float)D_MODEL) + 1e-5f);
    float4 wv = *(const float4*)(w + t * 4);
    ushort4 o;
    o.x = f2bf(r.x * scale * wv.x);
    o.y = f2bf(r.y * scale * wv.y);
    o.z = f2bf(r.z * scale * wv.z);
    o.w = f2bf(r.w * scale * wv.w);
    *(ushort4*)(xout + base) = o;
}

// ---------------- bf16 MFMA TN GEMM (reg-staged; WF32 converts weight in-flight) ---
// Linear grid, XCD-banded decode: j=(id%8)*T+id/8; (n,m,ks) with ks,m fastest.
// NO __launch_bounds__: lets compiler park acc in AGPRs (VGPR~60, occupancy ~40%).
template<int ATOMIC, int WF32>
__global__ void gemm_bf16_mfma_kernel(const ushort* __restrict__ A,
                                      const void* __restrict__ Wv,
                                      float* __restrict__ C,
                                      int N, int K, int lda, int ldc,
                                      int MB, int KS) {
    __shared__ ushort As[128][40];
    __shared__ ushort Ws[128][40];
    const int t  = threadIdx.x;
    const int T  = gridDim.x >> 3;
    const int id = blockIdx.x;
    const int j  = (id & 7) * T + (id >> 3);
    const int ks  = j % KS;
    const int rem = j / KS;
    const int m0 = (rem % MB) * 128;
    const int n0 = (rem / MB) * 128;
    const int kchunk = K / KS;
    const int kbeg = ks * kchunk;
    const int kend = kbeg + kchunk;

    const int srow = t >> 1;
    const int skc  = (t & 1) * 16;
    const ushort* Ag = A + (size_t)(m0 + srow) * lda + skc;
    const bool wvld = (n0 + srow) < N;
    const ushort* Wg   = (const ushort*)Wv + (size_t)(wvld ? (n0 + srow) : 0) * K + skc;
    const float*  Wg32 = (const float*)Wv  + (size_t)(wvld ? (n0 + srow) : 0) * K + skc;

    const int lane = t & 63;
    const int wm = (t >> 7) & 1;
    const int wn = (t >> 6) & 1;
    const int lr = lane & 15;
    const int lk = lane >> 4;

    f32x4 acc[4][4] = {};
    const short8 zero8 = {0, 0, 0, 0, 0, 0, 0, 0};
    const float4 zf4 = make_float4(0.f, 0.f, 0.f, 0.f);

    short8 a0 = *(const short8*)(Ag + kbeg);
    short8 a1 = *(const short8*)(Ag + kbeg + 8);
    short8 w0, w1;
    float4 wf0, wf1, wf2, wf3;
    if constexpr (WF32) {
        wf0 = wvld ? *(const float4*)(Wg32 + kbeg)      : zf4;
        wf1 = wvld ? *(const float4*)(Wg32 + kbeg + 4)  : zf4;
        wf2 = wvld ? *(const float4*)(Wg32 + kbeg + 8)  : zf4;
        wf3 = wvld ? *(const float4*)(Wg32 + kbeg + 12) : zf4;
    } else {
        w0 = wvld ? *(const short8*)(Wg + kbeg)     : zero8;
        w1 = wvld ? *(const short8*)(Wg + kbeg + 8) : zero8;
    }

    for (int k0 = kbeg;;) {
        *(short8*)&As[srow][skc]     = a0;
        *(short8*)&As[srow][skc + 8] = a1;
        if constexpr (WF32) {
            *(short8*)&Ws[srow][skc]     = pack8(wf0, wf1);
            *(short8*)&Ws[srow][skc + 8] = pack8(wf2, wf3);
        } else {
            *(short8*)&Ws[srow][skc]     = w0;
            *(short8*)&Ws[srow][skc + 8] = w1;
        }
        __syncthreads();

        k0 += 32;
        const bool more = k0 < kend;
        if (more) {
            a0 = *(const short8*)(Ag + k0);
            a1 = *(const short8*)(Ag + k0 + 8);
            if (wvld) {
                if constexpr (WF32) {
                    wf0 = *(const float4*)(Wg32 + k0);
                    wf1 = *(const float4*)(Wg32 + k0 + 4);
                    wf2 = *(const float4*)(Wg32 + k0 + 8);
                    wf3 = *(const float4*)(Wg32 + k0 + 12);
                } else {
                    w0 = *(const short8*)(Wg + k0);
                    w1 = *(const short8*)(Wg + k0 + 8);
                }
            }
        }

        short8 af[4], bfr[4];
        #pragma unroll
        for (int m = 0; m < 4; ++m)
            af[m] = *(const short8*)&As[wm * 64 + m * 16 + lr][lk * 8];
        #pragma unroll
        for (int n = 0; n < 4; ++n)
            bfr[n] = *(const short8*)&Ws[wn * 64 + n * 16 + lr][lk * 8];
        #pragma unroll
        for (int m = 0; m < 4; ++m)
            #pragma unroll
            for (int n = 0; n < 4; ++n)
                acc[m][n] = __builtin_amdgcn_mfma_f32_16x16x32_bf16(
                    af[m], bfr[n], acc[m][n], 0, 0, 0);

        if (!more) break;
        __syncthreads();
    }

    #pragma unroll
    for (int m = 0; m < 4; ++m) {
        const int row = m0 + wm * 64 + m * 16 + lk * 4;
        #pragma unroll
        for (int n = 0; n < 4; ++n) {
            const int col = n0 + wn * 64 + n * 16 + lr;
            if (col < N) {
                #pragma unroll
                for (int r = 0; r < 4; ++r) {
                    if (ATOMIC)
                        atomicAdd(&C[(size_t)(row + r) * ldc + col], acc[m][n][r]);
                    else
                        C[(size_t)(row + r) * ldc + col] = acc[m][n][r];
                }
            }
        }
    }
}

// ---------------- bf16 MFMA TN GEMM, global_load_lds staging (m97 pattern) -------
// Pure-bf16 operands, linear LDS [128][32], double-buffered, 1 barrier/K-step.
// W must be padded so rows up to gridDim-implied N_pad are readable.
__global__ void gemm_bf16_gld_kernel(const ushort* __restrict__ A,
                                     const ushort* __restrict__ W,
                                     float* __restrict__ C,
                                     int N, int K, int lda, int ldc, int MB) {
    __shared__ ushort As[2][128][32];
    __shared__ ushort Ws[2][128][32];
    const int t  = threadIdx.x;
    const int T  = gridDim.x >> 3;
    const int id = blockIdx.x;
    const int j  = (id & 7) * T + (id >> 3);
    const int m0 = (j % MB) * 128;
    const int n0 = (j / MB) * 128;

    const int lane = t & 63;
    const int w    = t >> 6;                 // wave 0..3
    // staging: instr i covers rows i*64 + w*16 + (lane>>2), 16B col chunk lane&3
    const int srow = w * 16 + (lane >> 2);
    const int scol = (lane & 3) * 8;         // elements
    const ushort* Ag0 = A + (size_t)(m0 + srow) * lda + scol;
    const ushort* Ag1 = A + (size_t)(m0 + srow + 64) * lda + scol;
    const ushort* Wg0 = W + (size_t)(n0 + srow) * K + scol;
    const ushort* Wg1 = W + (size_t)(n0 + srow + 64) * K + scol;

    const int wm = (t >> 7) & 1;
    const int wn = (t >> 6) & 1;
    const int lr = lane & 15;
    const int lk = lane >> 4;

    f32x4 acc[4][4] = {};

#define STAGE_GLD(buf, kk)                                                        \
    do {                                                                          \
        __builtin_amdgcn_global_load_lds((GUint*)(Ag0 + (kk)),                    \
            (LUint*)&As[buf][w * 16][0], 16, 0, 0);                               \
        __builtin_amdgcn_global_load_lds((GUint*)(Ag1 + (kk)),                    \
            (LUint*)&As[buf][64 + w * 16][0], 16, 0, 0);                          \
        __builtin_amdgcn_global_load_lds((GUint*)(Wg0 + (kk)),                    \
            (LUint*)&Ws[buf][w * 16][0], 16, 0, 0);                               \
        __builtin_amdgcn_global_load_lds((GUint*)(Wg1 + (kk)),                    \
            (LUint*)&Ws[buf][64 + w * 16][0], 16, 0, 0);                          \
    } while (0)

    STAGE_GLD(0, 0);
    int buf = 0;
    for (int k0 = 0;;) {
        __syncthreads();   // waitcnt vmcnt(0) lgkmcnt(0) + barrier: buf ready
        const bool more = (k0 + 32) < K;
        if (more) STAGE_GLD(buf ^ 1, k0 + 32);

        short8 af[4], bfr[4];
        #pragma unroll
        for (int m = 0; m < 4; ++m)
            af[m] = *(const short8*)&As[buf][wm * 64 + m * 16 + lr][lk * 8];
        #pragma unroll
        for (int n = 0; n < 4; ++n)
            bfr[n] = *(const short8*)&Ws[buf][wn * 64 + n * 16 + lr][lk * 8];
        #pragma unroll
        for (int m = 0; m < 4; ++m)
            #pragma unroll
            for (int n = 0; n < 4; ++n)
                acc[m][n] = __builtin_amdgcn_mfma_f32_16x16x32_bf16(
                    af[m], bfr[n], acc[m][n], 0, 0, 0);

        if (!more) break;
        buf ^= 1;
        k0 += 32;
    }
#undef STAGE_GLD

    #pragma unroll
    for (int m = 0; m < 4; ++m) {
        const int row = m0 + wm * 64 + m * 16 + lk * 4;
        #pragma unroll
        for (int n = 0; n < 4; ++n) {
            const int col = n0 + wn * 64 + n * 16 + lr;
            if (col < N) {
                #pragma unroll
                for (int r = 0; r < 4; ++r)
                    C[(size_t)(row + r) * ldc + col] = acc[m][n][r];
            }
        }
    }
}

// ---------------- fp32 TN GEMM (dt_proj only) ----------------
template<int EPI>
__global__ void gemm_tn_kernel(const float* __restrict__ A,
                               const float* __restrict__ W,
                               const float* __restrict__ bias,
                               float* __restrict__ C,
                               int M, int N, int K, int lda) {
    __shared__ float As[16][68];
    __shared__ float Ws[16][68];
    const int t  = threadIdx.x;
    const int m0 = blockIdx.y * 64;
    const int n0 = blockIdx.x * 64;
    const int lrow = t >> 2;
    const int lkq  = (t & 3) * 4;
    const int tx = t & 15;
    const int ty = t >> 4;

    const float* Arow = A + (size_t)(m0 + lrow) * lda;
    const int   wr    = n0 + lrow;
    const bool  wvalid = wr < N;
    const float* Wrow = W + (size_t)(wvalid ? wr : 0) * K;

    float acc[4][4] = {};
    for (int k0 = 0; k0 < K; k0 += 16) {
        float4 av = *(const float4*)(Arow + k0 + lkq);
        float4 wv = wvalid ? *(const float4*)(Wrow + k0 + lkq)
                           : make_float4(0.f, 0.f, 0.f, 0.f);
        As[lkq + 0][lrow] = av.x; As[lkq + 1][lrow] = av.y;
        As[lkq + 2][lrow] = av.z; As[lkq + 3][lrow] = av.w;
        Ws[lkq + 0][lrow] = wv.x; Ws[lkq + 1][lrow] = wv.y;
        Ws[lkq + 2][lrow] = wv.z; Ws[lkq + 3][lrow] = wv.w;
        __syncthreads();
        #pragma unroll
        for (int kk = 0; kk < 16; ++kk) {
            float4 a = *(const float4*)&As[kk][ty * 4];
            float4 b = *(const float4*)&Ws[kk][tx * 4];
            #pragma unroll
            for (int i = 0; i < 4; ++i) {
                float ai = (i == 0) ? a.x : (i == 1) ? a.y : (i == 2) ? a.z : a.w;
                acc[i][0] = fmaf(ai, b.x, acc[i][0]);
                acc[i][1] = fmaf(ai, b.y, acc[i][1]);
                acc[i][2] = fmaf(ai, b.z, acc[i][2]);
                acc[i][3] = fmaf(ai, b.w, acc[i][3]);
            }
        }
        __syncthreads();
    }

    const int colb = n0 + tx * 4;
    if (colb < N) {
        #pragma unroll
        for (int i = 0; i < 4; ++i) {
            int row = m0 + ty * 4 + i;
            float4 v = make_float4(acc[i][0], acc[i][1], acc[i][2], acc[i][3]);
            if (EPI == 1) {
                v.x = softplus_f(v.x + bias[colb + 0]);
                v.y = softplus_f(v.y + bias[colb + 1]);
                v.z = softplus_f(v.z + bias[colb + 2]);
                v.w = softplus_f(v.w + bias[colb + 3]);
            }
            *(float4*)(C + (size_t)row * N + colb) = v;
        }
    }
}

// ---------------- depthwise causal conv (k=4) + silu ----------------
__global__ void conv_silu_kernel(const float* __restrict__ xz,
                                 const float* __restrict__ cw,
                                 const float* __restrict__ cb,
                                 float* __restrict__ u,
                                 ushort* __restrict__ u_b) {
    int idx = blockIdx.x * 256 + threadIdx.x;
    int l = idx >> 11;
    int c = idx & 2047;
    float acc = cb[c];
    float w0 = cw[c * 4 + 0], w1 = cw[c * 4 + 1], w2 = cw[c * 4 + 2], w3 = cw[c * 4 + 3];
    if (l >= 3) acc = fmaf(xz[(size_t)(l - 3) * 4096 + c], w0, acc);
    if (l >= 2) acc = fmaf(xz[(size_t)(l - 2) * 4096 + c], w1, acc);
    if (l >= 1) acc = fmaf(xz[(size_t)(l - 1) * 4096 + c], w2, acc);
    acc = fmaf(xz[(size_t)l * 4096 + c], w3, acc);
    float s = silu_f(acc);
    u[idx] = s;
    u_b[idx] = f2bf(s);
}

// ---------------- chunked selective scan ----------------
__global__ void scan_a_kernel(const float* __restrict__ u,
                              const float* __restrict__ dt,
                              const float* __restrict__ xdbl,
                              const float* __restrict__ A_log,
                              float* __restrict__ yloc,     // stride 4096 (xz xp half)
                              float* __restrict__ cumdt,    // [l][d]
                              float* __restrict__ s_end) {  // [d][c][n]
    const int idx = blockIdx.x * 256 + threadIdx.x;   // 65536
    const int d = idx & 2047;
    const int c = idx >> 11;

    float Aa[16];
    #pragma unroll
    for (int q = 0; q < 4; ++q) {
        float4 al = *(const float4*)(A_log + (size_t)d * 16 + q * 4);
        Aa[q * 4 + 0] = -__expf(al.x);
        Aa[q * 4 + 1] = -__expf(al.y);
        Aa[q * 4 + 2] = -__expf(al.z);
        Aa[q * 4 + 3] = -__expf(al.w);
    }

    float s[16];
    #pragma unroll
    for (int n = 0; n < 16; ++n) s[n] = 0.0f;
    float cd = 0.0f;

    const int l0 = c * CLEN;
    for (int i = 0; i < CLEN; ++i) {
        const int l = l0 + i;
        const float dtl = dt[(size_t)l * 2048 + d];
        const float ul  = u[(size_t)l * 2048 + d];
        float Bn[16], Cn[16];
        const float* xbp = xdbl + (size_t)l * 96;
        *(float4*)&Bn[0]  = *(const float4*)(xbp + 64);
        *(float4*)&Bn[4]  = *(const float4*)(xbp + 68);
        *(float4*)&Bn[8]  = *(const float4*)(xbp + 72);
        *(float4*)&Bn[12] = *(const float4*)(xbp + 76);
        *(float4*)&Cn[0]  = *(const float4*)(xbp + 80);
        *(float4*)&Cn[4]  = *(const float4*)(xbp + 84);
        *(float4*)&Cn[8]  = *(const float4*)(xbp + 88);
        *(float4*)&Cn[12] = *(const float4*)(xbp + 92);
        cd += dtl;
        const float dtu = dtl * ul;
        float y = 0.0f;
        #pragma unroll
        for (int n = 0; n < 16; ++n) {
            float dA = __expf(dtl * Aa[n]);
            s[n] = fmaf(s[n], dA, dtu * Bn[n]);
            y = fmaf(s[n], Cn[n], y);
        }
        yloc[(size_t)l * 4096 + d] = y;
        cumdt[(size_t)l * 2048 + d] = cd;
    }
    float* se = s_end + ((size_t)d * NCHUNK + c) * 16;
    #pragma unroll
    for (int q = 0; q < 4; ++q)
        *(float4*)(se + q * 4) = make_float4(s[q * 4], s[q * 4 + 1], s[q * 4 + 2], s[q * 4 + 3]);
}

__global__ void scan_b_kernel(const float* __restrict__ s_end,
                              const float* __restrict__ cumdt,
                              const float* __restrict__ A_log,
                              float* __restrict__ s_in) {
    const int idx = blockIdx.x * 256 + threadIdx.x;   // 32768
    const int d = idx >> 4;
    const int n = idx & 15;
    const float Aa = -__expf(A_log[(size_t)d * 16 + n]);
    float s = 0.0f;
    #pragma unroll
    for (int c = 0; c < NCHUNK; ++c) {
        s_in[((size_t)d * NCHUNK + c) * 16 + n] = s;
        const float tot = cumdt[(size_t)(c * CLEN + CLEN - 1) * 2048 + d];
        s = s_end[((size_t)d * NCHUNK + c) * 16 + n] + __expf(Aa * tot) * s;
    }
}

__global__ void scan_c_kernel(const float* __restrict__ u,
                              const float* __restrict__ xdbl,
                              const float* __restrict__ A_log,
                              const float* __restrict__ Dv,
                              const float* __restrict__ xz,
                              const float* __restrict__ cumdt,
                              const float* __restrict__ s_in,
                              ushort* __restrict__ yb) {
    const int idx = blockIdx.x * 256 + threadIdx.x;   // l*2048+d
    const int l = idx >> 11;
    const int d = idx & 2047;
    const int c = l >> 5;   // CLEN=32

    const float cd = cumdt[idx];
    const float ul = u[idx];
    const float yv = xz[(size_t)l * 4096 + d];
    const float zv = xz[(size_t)l * 4096 + 2048 + d];
    const float* Cp = xdbl + (size_t)l * 96 + 80;
    const float* si = s_in + ((size_t)d * NCHUNK + c) * 16;

    float corr = 0.0f;
    #pragma unroll
    for (int q = 0; q < 4; ++q) {
        float4 al = *(const float4*)(A_log + (size_t)d * 16 + q * 4);
        float4 cv = *(const float4*)(Cp + q * 4);
        float4 sv = *(const float4*)(si + q * 4);
        corr = fmaf(cv.x * __expf(-__expf(al.x) * cd), sv.x, corr);
        corr = fmaf(cv.y * __expf(-__expf(al.y) * cd), sv.y, corr);
        corr = fmaf(cv.z * __expf(-__expf(al.z) * cd), sv.z, corr);
        corr = fmaf(cv.w * __expf(-__expf(al.w) * cd), sv.w, corr);
    }
    const float y = (yv + corr + Dv[d] * ul) * silu_f(zv);
    yb[idx] = f2bf(y);
}

extern "C" void kernel_launch(void* const* d_in, const int* in_sizes, int n_in,
                              void* d_out, int out_size, void* d_ws, size_t ws_size,
                              hipStream_t stream) {
    const int*   ids        = (const int*)d_in[0];
    const float* emb        = (const float*)d_in[1];
    const float* norm_w     = (const float*)d_in[2];
    const float* in_proj_w  = (const float*)d_in[3];
    const float* conv_w     = (const float*)d_in[4];
    const float* conv_b     = (const float*)d_in[5];
    const float* x_proj_w   = (const float*)d_in[6];
    const float* dt_proj_w  = (const float*)d_in[7];
    const float* dt_proj_b  = (const float*)d_in[8];
    const float* A_log      = (const float*)d_in[9];
    const float* Dv         = (const float*)d_in[10];
    const float* out_proj_w = (const float*)d_in[11];
    const float* norm_f_w   = (const float*)d_in[12];
    float* out = (float*)d_out;

    // ---- workspace layout ----
    char* p = (char*)d_ws;
    ushort* emb_b  = (ushort*)p; p += (size_t)VOCAB_PAD * D_MODEL * 2;    // 103 MB (padded)
    float* residual = (float*)p; p += (size_t)SEQ_L * D_MODEL * 4;
    float* hidden   = (float*)p; p += (size_t)SEQ_L * D_MODEL * 4;
    ushort* xb      = (ushort*)p; p += (size_t)SEQ_L * D_MODEL * 2;
    float* xz       = (float*)p; p += (size_t)SEQ_L * 4096 * 4;
    float* u        = (float*)p; p += (size_t)SEQ_L * 2048 * 4;
    ushort* u_b     = (ushort*)p; p += (size_t)SEQ_L * 2048 * 2;
    float* dtb      = (float*)p; p += (size_t)SEQ_L * 2048 * 4;
    float* xdbl     = (float*)p; p += (size_t)SEQ_L * 96 * 4;
    ushort* yb      = (ushort*)p; p += (size_t)SEQ_L * 2048 * 2;
    float* cumdt    = (float*)p; p += (size_t)SEQ_L * 2048 * 4;
    float* s_end    = (float*)p; p += (size_t)D_INNER * NCHUNK * 16 * 4;
    float* s_in     = (float*)p; p += (size_t)D_INNER * NCHUNK * 16 * 4;

    dim3 blk(256);

    // embedding -> bf16 (LM-head weight; halves its HBM stream)
    f32_to_bf16_kernel<<<dim3(VOCAB * D_MODEL / 4 / 256), blk, 0, stream>>>(
        emb, emb_b, VOCAB * D_MODEL / 4);

    embed_kernel<<<dim3(SEQ_L), blk, 0, stream>>>(ids, emb, hidden);

    for (int i = 0; i < N_LAYER; ++i) {
        add_rmsnorm_kernel<<<dim3(SEQ_L), blk, 0, stream>>>(
            residual, hidden, norm_w + (size_t)i * D_MODEL, xb, i == 0 ? 0 : 1);

        // xz = x @ in_proj^T : M=1024 N=4096 K=1024  (NB=32, MB=8, KS=1 -> 256 blocks)
        gemm_bf16_mfma_kernel<0, 1><<<dim3(256), blk, 0, stream>>>(
            xb, in_proj_w + (size_t)i * 4096 * 1024, xz, 4096, 1024, 1024, 4096, 8, 1);

        conv_silu_kernel<<<dim3(SEQ_L * D_INNER / 256), blk, 0, stream>>>(
            xz, conv_w + (size_t)i * D_INNER * D_CONV, conv_b + (size_t)i * D_INNER,
            u, u_b);

        // xdbl = u @ x_proj^T : M=1024 N=96 K=2048  (NB=1, MB=8, KS=16 -> 128 blocks)
        zero_kernel<<<dim3(SEQ_L * 96 / 4 / 256), blk, 0, stream>>>(xdbl, SEQ_L * 96 / 4);
        gemm_bf16_mfma_kernel<1, 1><<<dim3(128), blk, 0, stream>>>(
            u_b, x_proj_w + (size_t)i * 96 * 2048, xdbl, 96, 2048, 2048, 96, 8, 16);

        // dt = softplus(dt_r @ dt_proj^T + b)
        gemm_tn_kernel<1><<<dim3(D_INNER / 64, SEQ_L / 64), blk, 0, stream>>>(
            xdbl, dt_proj_w + (size_t)i * D_INNER * DT_RANK,
            dt_proj_b + (size_t)i * D_INNER, dtb,
            SEQ_L, D_INNER, DT_RANK, 96);

        // chunked scan
        scan_a_kernel<<<dim3(D_INNER * NCHUNK / 256), blk, 0, stream>>>(
            u, dtb, xdbl, A_log + (size_t)i * D_INNER * D_STATE, xz, cumdt, s_end);
        scan_b_kernel<<<dim3(D_INNER * 16 / 256), blk, 0, stream>>>(
            s_end, cumdt, A_log + (size_t)i * D_INNER * D_STATE, s_in);
        scan_c_kernel<<<dim3(SEQ_L * D_INNER / 256), blk, 0, stream>>>(
            u, xdbl, A_log + (size_t)i * D_INNER * D_STATE,
            Dv + (size_t)i * D_INNER, xz, cumdt, s_in, yb);

        // hidden = y @ out_proj^T : M=1024 N=1024 K=2048 (NB=8, MB=8, KS=4 -> 256 blocks)
        zero_kernel<<<dim3(SEQ_L * D_MODEL / 4 / 256), blk, 0, stream>>>(
            hidden, SEQ_L * D_MODEL / 4);
        gemm_bf16_mfma_kernel<1, 1><<<dim3(256), blk, 0, stream>>>(
            yb, out_proj_w + (size_t)i * 1024 * 2048, hidden, 1024, 2048, 2048, 1024, 8, 4);
    }

    add_rmsnorm_kernel<<<dim3(SEQ_L), blk, 0, stream>>>(
        residual, hidden, norm_f_w, xb, 1);

    // logits = hf @ emb^T : M=1024 N=50280 K=1024 (NB=393, MB=8 -> 3144 blocks, GLD path)
    gemm_bf16_gld_kernel<<<dim3(3144), blk, 0, stream>>>(
        xb, emb_b, out, VOCAB, 1024, 1024, VOCAB, 8);
}

// Round 6
// 846.035 us; speedup vs baseline: 5.9321x; 1.0827x over previous
//
#include <hip/hip_runtime.h>
#include <hip/hip_bf16.h>

#define D_MODEL 1024
#define N_LAYER 4
#define D_INNER 2048
#define D_STATE 16
#define D_CONV  4
#define DT_RANK 64
#define SEQ_L   1024
#define VOCAB   50280
#define VOCAB_PAD 50304   // 393*128
#define NCHUNK  32
#define CLEN    32

typedef __attribute__((ext_vector_type(8))) short short8;
typedef __attribute__((ext_vector_type(4))) float f32x4;

typedef __attribute__((address_space(1))) const unsigned GUint;
typedef __attribute__((address_space(3))) unsigned LUint;

__device__ __forceinline__ float silu_f(float x) {
    return x / (1.0f + __expf(-x));
}
__device__ __forceinline__ float softplus_f(float x) {
    return fmaxf(x, 0.0f) + log1pf(__expf(-fabsf(x)));
}
__device__ __forceinline__ ushort f2bf(float f) {
    union { float f; unsigned u; } uf; uf.f = f;
    unsigned r = uf.u + 0x7FFF + ((uf.u >> 16) & 1);   // RNE
    return (ushort)(r >> 16);
}

// ---------------- fp32 -> bf16 bulk convert ----------------
__global__ void f32_to_bf16_kernel(const float* __restrict__ in,
                                   ushort* __restrict__ out, int n4) {
    int i = blockIdx.x * 256 + threadIdx.x;
    if (i >= n4) return;
    float4 v = *(const float4*)(in + (size_t)i * 4);
    ushort4 o;
    o.x = f2bf(v.x); o.y = f2bf(v.y); o.z = f2bf(v.z); o.w = f2bf(v.w);
    *(ushort4*)(out + (size_t)i * 4) = o;
}

// x_proj weights: (4,96,2048) fp32 -> (4,128,2048) bf16 with zero-filled pad rows
__global__ void xpw_convert_kernel(const float* __restrict__ src,
                                   ushort* __restrict__ dst) {
    int q = blockIdx.x * 256 + threadIdx.x;   // quad index, total 4*128*512
    int layer = q / (128 * 512);
    int rq    = q % (128 * 512);
    int row   = rq / 512;
    int cq    = rq % 512;
    ushort4 o;
    if (row < 96) {
        float4 v = *(const float4*)(src + ((size_t)layer * 96 + row) * 2048 + cq * 4);
        o.x = f2bf(v.x); o.y = f2bf(v.y); o.z = f2bf(v.z); o.w = f2bf(v.w);
    } else {
        o.x = o.y = o.z = o.w = 0;
    }
    *(ushort4*)(dst + (size_t)q * 4) = o;
}

__global__ void zero_kernel(float* __restrict__ p, int n4) {
    int i = blockIdx.x * 256 + threadIdx.x;
    if (i < n4) *(float4*)(p + (size_t)i * 4) = make_float4(0.f, 0.f, 0.f, 0.f);
}

// ---------------- embedding gather ----------------
__global__ void embed_kernel(const int* __restrict__ ids,
                             const float* __restrict__ emb,
                             float* __restrict__ hidden) {
    int l = blockIdx.x;
    int t = threadIdx.x;
    int id = ids[l];
    float4 v = *(const float4*)(emb + (size_t)id * D_MODEL + t * 4);
    *(float4*)(hidden + (size_t)l * D_MODEL + t * 4) = v;
}

// ---------------- residual add + RMSNorm -> bf16 x ----------------
__global__ void add_rmsnorm_kernel(float* __restrict__ res,
                                   const float* __restrict__ h,
                                   const float* __restrict__ w,
                                   ushort* __restrict__ xout,
                                   int add) {
    int l = blockIdx.x;
    int t = threadIdx.x;
    size_t base = (size_t)l * D_MODEL + t * 4;
    float4 hv = *(const float4*)(h + base);
    float4 r;
    if (add) {
        r = *(const float4*)(res + base);
        r.x += hv.x; r.y += hv.y; r.z += hv.z; r.w += hv.w;
    } else {
        r = hv;
    }
    *(float4*)(res + base) = r;
    float ss = r.x * r.x + r.y * r.y + r.z * r.z + r.w * r.w;
    #pragma unroll
    for (int off = 32; off > 0; off >>= 1) ss += __shfl_down(ss, off, 64);
    __shared__ float sred[4];
    if ((t & 63) == 0) sred[t >> 6] = ss;
    __syncthreads();
    float tot = sred[0] + sred[1] + sred[2] + sred[3];
    float scale = rsqrtf(tot * (1.0f / (float)D_MODEL) + 1e-5f);
    float4 wv = *(const float4*)(w + t * 4);
    ushort4 o;
    o.x = f2bf(r.x * scale * wv.x);
    o.y = f2bf(r.y * scale * wv.y);
    o.z = f2bf(r.z * scale * wv.z);
    o.w = f2bf(r.w * scale * wv.w);
    *(ushort4*)(xout + base) = o;
}

// ---------------- bf16 MFMA TN GEMM, global_load_lds staging (m97 pattern) -------
// Pure-bf16 operands, linear LDS [128][32], double-buffered, 1 barrier/K-step.
// Linear grid, XCD-banded decode: j=(id%8)*T+id/8; (n, m, ks) with ks,m fastest.
// Optional split-K (KS>1) with atomicAdd epilogue (ATOMIC=1, C pre-zeroed).
// W rows must be readable up to padded N (pad rows zero-filled); M%128==0.
template<int ATOMIC>
__global__ void gemm_bf16_gld_kernel(const ushort* __restrict__ A,
                                     const ushort* __restrict__ W,
                                     float* __restrict__ C,
                                     int N, int K, int lda, int ldc,
                                     int MB, int KS) {
    __shared__ ushort As[2][128][32];
    __shared__ ushort Ws[2][128][32];
    const int t  = threadIdx.x;
    const int T  = gridDim.x >> 3;
    const int id = blockIdx.x;
    const int j  = (id & 7) * T + (id >> 3);
    const int ks  = j % KS;
    const int rem = j / KS;
    const int m0 = (rem % MB) * 128;
    const int n0 = (rem / MB) * 128;
    const int kchunk = K / KS;
    const int kbeg = ks * kchunk;
    const int kend = kbeg + kchunk;

    const int lane = t & 63;
    const int w    = t >> 6;                 // wave 0..3
    // staging: wave w covers rows w*16 + (lane>>2) (+64), 16B col chunk lane&3
    const int srow = w * 16 + (lane >> 2);
    const int scol = (lane & 3) * 8;         // elements
    const ushort* Ag0 = A + (size_t)(m0 + srow) * lda + scol;
    const ushort* Ag1 = A + (size_t)(m0 + srow + 64) * lda + scol;
    const ushort* Wg0 = W + (size_t)(n0 + srow) * K + scol;
    const ushort* Wg1 = W + (size_t)(n0 + srow + 64) * K + scol;

    const int wm = (t >> 7) & 1;
    const int wn = (t >> 6) & 1;
    const int lr = lane & 15;
    const int lk = lane >> 4;

    f32x4 acc[4][4] = {};

#define STAGE_GLD(buf, kk)                                                        \
    do {                                                                          \
        __builtin_amdgcn_global_load_lds((GUint*)(Ag0 + (kk)),                    \
            (LUint*)&As[buf][w * 16][0], 16, 0, 0);                               \
        __builtin_amdgcn_global_load_lds((GUint*)(Ag1 + (kk)),                    \
            (LUint*)&As[buf][64 + w * 16][0], 16, 0, 0);                          \
        __builtin_amdgcn_global_load_lds((GUint*)(Wg0 + (kk)),                    \
            (LUint*)&Ws[buf][w * 16][0], 16, 0, 0);                               \
        __builtin_amdgcn_global_load_lds((GUint*)(Wg1 + (kk)),                    \
            (LUint*)&Ws[buf][64 + w * 16][0], 16, 0, 0);                          \
    } while (0)

    STAGE_GLD(0, kbeg);
    int buf = 0;
    for (int k0 = kbeg;;) {
        __syncthreads();   // vmcnt(0)+lgkmcnt(0)+barrier: buf ready
        const bool more = (k0 + 32) < kend;
        if (more) STAGE_GLD(buf ^ 1, k0 + 32);

        short8 af[4], bfr[4];
        #pragma unroll
        for (int m = 0; m < 4; ++m)
            af[m] = *(const short8*)&As[buf][wm * 64 + m * 16 + lr][lk * 8];
        #pragma unroll
        for (int n = 0; n < 4; ++n)
            bfr[n] = *(const short8*)&Ws[buf][wn * 64 + n * 16 + lr][lk * 8];
        #pragma unroll
        for (int m = 0; m < 4; ++m)
            #pragma unroll
            for (int n = 0; n < 4; ++n)
                acc[m][n] = __builtin_amdgcn_mfma_f32_16x16x32_bf16(
                    af[m], bfr[n], acc[m][n], 0, 0, 0);

        if (!more) break;
        buf ^= 1;
        k0 += 32;
    }
#undef STAGE_GLD

    #pragma unroll
    for (int m = 0; m < 4; ++m) {
        const int row = m0 + wm * 64 + m * 16 + lk * 4;
        #pragma unroll
        for (int n = 0; n < 4; ++n) {
            const int col = n0 + wn * 64 + n * 16 + lr;
            if (col < N) {
                #pragma unroll
                for (int r = 0; r < 4; ++r) {
                    if (ATOMIC)
                        atomicAdd(&C[(size_t)(row + r) * ldc + col], acc[m][n][r]);
                    else
                        C[(size_t)(row + r) * ldc + col] = acc[m][n][r];
                }
            }
        }
    }
}

// ---------------- fp32 TN GEMM (dt_proj only) ----------------
template<int EPI>
__global__ void gemm_tn_kernel(const float* __restrict__ A,
                               const float* __restrict__ W,
                               const float* __restrict__ bias,
                               float* __restrict__ C,
                               int M, int N, int K, int lda) {
    __shared__ float As[16][68];
    __shared__ float Ws[16][68];
    const int t  = threadIdx.x;
    const int m0 = blockIdx.y * 64;
    const int n0 = blockIdx.x * 64;
    const int lrow = t >> 2;
    const int lkq  = (t & 3) * 4;
    const int tx = t & 15;
    const int ty = t >> 4;

    const float* Arow = A + (size_t)(m0 + lrow) * lda;
    const int   wr    = n0 + lrow;
    const bool  wvalid = wr < N;
    const float* Wrow = W + (size_t)(wvalid ? wr : 0) * K;

    float acc[4][4] = {};
    for (int k0 = 0; k0 < K; k0 += 16) {
        float4 av = *(const float4*)(Arow + k0 + lkq);
        float4 wv = wvalid ? *(const float4*)(Wrow + k0 + lkq)
                           : make_float4(0.f, 0.f, 0.f, 0.f);
        As[lkq + 0][lrow] = av.x; As[lkq + 1][lrow] = av.y;
        As[lkq + 2][lrow] = av.z; As[lkq + 3][lrow] = av.w;
        Ws[lkq + 0][lrow] = wv.x; Ws[lkq + 1][lrow] = wv.y;
        Ws[lkq + 2][lrow] = wv.z; Ws[lkq + 3][lrow] = wv.w;
        __syncthreads();
        #pragma unroll
        for (int kk = 0; kk < 16; ++kk) {
            float4 a = *(const float4*)&As[kk][ty * 4];
            float4 b = *(const float4*)&Ws[kk][tx * 4];
            #pragma unroll
            for (int i = 0; i < 4; ++i) {
                float ai = (i == 0) ? a.x : (i == 1) ? a.y : (i == 2) ? a.z : a.w;
                acc[i][0] = fmaf(ai, b.x, acc[i][0]);
                acc[i][1] = fmaf(ai, b.y, acc[i][1]);
                acc[i][2] = fmaf(ai, b.z, acc[i][2]);
                acc[i][3] = fmaf(ai, b.w, acc[i][3]);
            }
        }
        __syncthreads();
    }

    const int colb = n0 + tx * 4;
    if (colb < N) {
        #pragma unroll
        for (int i = 0; i < 4; ++i) {
            int row = m0 + ty * 4 + i;
            float4 v = make_float4(acc[i][0], acc[i][1], acc[i][2], acc[i][3]);
            if (EPI == 1) {
                v.x = softplus_f(v.x + bias[colb + 0]);
                v.y = softplus_f(v.y + bias[colb + 1]);
                v.z = softplus_f(v.z + bias[colb + 2]);
                v.w = softplus_f(v.w + bias[colb + 3]);
            }
            *(float4*)(C + (size_t)row * N + colb) = v;
        }
    }
}

// ---------------- depthwise causal conv (k=4) + silu ----------------
__global__ void conv_silu_kernel(const float* __restrict__ xz,
                                 const float* __restrict__ cw,
                                 const float* __restrict__ cb,
                                 float* __restrict__ u,
                                 ushort* __restrict__ u_b) {
    int idx = blockIdx.x * 256 + threadIdx.x;
    int l = idx >> 11;
    int c = idx & 2047;
    float acc = cb[c];
    float w0 = cw[c * 4 + 0], w1 = cw[c * 4 + 1], w2 = cw[c * 4 + 2], w3 = cw[c * 4 + 3];
    if (l >= 3) acc = fmaf(xz[(size_t)(l - 3) * 4096 + c], w0, acc);
    if (l >= 2) acc = fmaf(xz[(size_t)(l - 2) * 4096 + c], w1, acc);
    if (l >= 1) acc = fmaf(xz[(size_t)(l - 1) * 4096 + c], w2, acc);
    acc = fmaf(xz[(size_t)l * 4096 + c], w3, acc);
    float s = silu_f(acc);
    u[idx] = s;
    u_b[idx] = f2bf(s);
}

// ---------------- chunked selective scan ----------------
__global__ void scan_a_kernel(const float* __restrict__ u,
                              const float* __restrict__ dt,
                              const float* __restrict__ xdbl,
                              const float* __restrict__ A_log,
                              float* __restrict__ yloc,     // stride 4096 (xz xp half)
                              float* __restrict__ cumdt,    // [l][d]
                              float* __restrict__ s_end) {  // [d][c][n]
    const int idx = blockIdx.x * 256 + threadIdx.x;   // 65536
    const int d = idx & 2047;
    const int c = idx >> 11;

    float Aa[16];
    #pragma unroll
    for (int q = 0; q < 4; ++q) {
        float4 al = *(const float4*)(A_log + (size_t)d * 16 + q * 4);
        Aa[q * 4 + 0] = -__expf(al.x);
        Aa[q * 4 + 1] = -__expf(al.y);
        Aa[q * 4 + 2] = -__expf(al.z);
        Aa[q * 4 + 3] = -__expf(al.w);
    }

    float s[16];
    #pragma unroll
    for (int n = 0; n < 16; ++n) s[n] = 0.0f;
    float cd = 0.0f;

    const int l0 = c * CLEN;
    for (int i = 0; i < CLEN; ++i) {
        const int l = l0 + i;
        const float dtl = dt[(size_t)l * 2048 + d];
        const float ul  = u[(size_t)l * 2048 + d];
        float Bn[16], Cn[16];
        const float* xbp = xdbl + (size_t)l * 96;
        *(float4*)&Bn[0]  = *(const float4*)(xbp + 64);
        *(float4*)&Bn[4]  = *(const float4*)(xbp + 68);
        *(float4*)&Bn[8]  = *(const float4*)(xbp + 72);
        *(float4*)&Bn[12] = *(const float4*)(xbp + 76);
        *(float4*)&Cn[0]  = *(const float4*)(xbp + 80);
        *(float4*)&Cn[4]  = *(const float4*)(xbp + 84);
        *(float4*)&Cn[8]  = *(const float4*)(xbp + 88);
        *(float4*)&Cn[12] = *(const float4*)(xbp + 92);
        cd += dtl;
        const float dtu = dtl * ul;
        float y = 0.0f;
        #pragma unroll
        for (int n = 0; n < 16; ++n) {
            float dA = __expf(dtl * Aa[n]);
            s[n] = fmaf(s[n], dA, dtu * Bn[n]);
            y = fmaf(s[n], Cn[n], y);
        }
        yloc[(size_t)l * 4096 + d] = y;
        cumdt[(size_t)l * 2048 + d] = cd;
    }
    float* se = s_end + ((size_t)d * NCHUNK + c) * 16;
    #pragma unroll
    for (int q = 0; q < 4; ++q)
        *(float4*)(se + q * 4) = make_float4(s[q * 4], s[q * 4 + 1], s[q * 4 + 2], s[q * 4 + 3]);
}

__global__ void scan_b_kernel(const float* __restrict__ s_end,
                              const float* __restrict__ cumdt,
                              const float* __restrict__ A_log,
                              float* __restrict__ s_in) {
    const int idx = blockIdx.x * 256 + threadIdx.x;   // 32768
    const int d = idx >> 4;
    const int n = idx & 15;
    const float Aa = -__expf(A_log[(size_t)d * 16 + n]);
    float s = 0.0f;
    #pragma unroll
    for (int c = 0; c < NCHUNK; ++c) {
        s_in[((size_t)d * NCHUNK + c) * 16 + n] = s;
        const float tot = cumdt[(size_t)(c * CLEN + CLEN - 1) * 2048 + d];
        s = s_end[((size_t)d * NCHUNK + c) * 16 + n] + __expf(Aa * tot) * s;
    }
}

__global__ void scan_c_kernel(const float* __restrict__ u,
                              const float* __restrict__ xdbl,
                              const float* __restrict__ A_log,
                              const float* __restrict__ Dv,
                              const float* __restrict__ xz,
                              const float* __restrict__ cumdt,
                              const float* __restrict__ s_in,
                              ushort* __restrict__ yb) {
    const int idx = blockIdx.x * 256 + threadIdx.x;   // l*2048+d
    const int l = idx >> 11;
    const int d = idx & 2047;
    const int c = l >> 5;   // CLEN=32

    const float cd = cumdt[idx];
    const float ul = u[idx];
    const float yv = xz[(size_t)l * 4096 + d];
    const float zv = xz[(size_t)l * 4096 + 2048 + d];
    const float* Cp = xdbl + (size_t)l * 96 + 80;
    const float* si = s_in + ((size_t)d * NCHUNK + c) * 16;

    float corr = 0.0f;
    #pragma unroll
    for (int q = 0; q < 4; ++q) {
        float4 al = *(const float4*)(A_log + (size_t)d * 16 + q * 4);
        float4 cv = *(const float4*)(Cp + q * 4);
        float4 sv = *(const float4*)(si + q * 4);
        corr = fmaf(cv.x * __expf(-__expf(al.x) * cd), sv.x, corr);
        corr = fmaf(cv.y * __expf(-__expf(al.y) * cd), sv.y, corr);
        corr = fmaf(cv.z * __expf(-__expf(al.z) * cd), sv.z, corr);
        corr = fmaf(cv.w * __expf(-__expf(al.w) * cd), sv.w, corr);
    }
    const float y = (yv + corr + Dv[d] * ul) * silu_f(zv);
    yb[idx] = f2bf(y);
}

extern "C" void kernel_launch(void* const* d_in, const int* in_sizes, int n_in,
                              void* d_out, int out_size, void* d_ws, size_t ws_size,
                              hipStream_t stream) {
    const int*   ids        = (const int*)d_in[0];
    const float* emb        = (const float*)d_in[1];
    const float* norm_w     = (const float*)d_in[2];
    const float* in_proj_w  = (const float*)d_in[3];
    const float* conv_w     = (const float*)d_in[4];
    const float* conv_b     = (const float*)d_in[5];
    const float* x_proj_w   = (const float*)d_in[6];
    const float* dt_proj_w  = (const float*)d_in[7];
    const float* dt_proj_b  = (const float*)d_in[8];
    const float* A_log      = (const float*)d_in[9];
    const float* Dv         = (const float*)d_in[10];
    const float* out_proj_w = (const float*)d_in[11];
    const float* norm_f_w   = (const float*)d_in[12];
    float* out = (float*)d_out;

    // ---- workspace layout ----
    char* p = (char*)d_ws;
    ushort* emb_b  = (ushort*)p; p += (size_t)VOCAB_PAD * D_MODEL * 2;      // 103 MB
    ushort* inw_b  = (ushort*)p; p += (size_t)N_LAYER * 4096 * 1024 * 2;    // 33.6 MB
    ushort* outw_b = (ushort*)p; p += (size_t)N_LAYER * 1024 * 2048 * 2;    // 16.8 MB
    ushort* xpw_b  = (ushort*)p; p += (size_t)N_LAYER * 128 * 2048 * 2;     //  2.1 MB (padded)
    float* residual = (float*)p; p += (size_t)SEQ_L * D_MODEL * 4;
    float* hidden   = (float*)p; p += (size_t)SEQ_L * D_MODEL * 4;          // adjacent to
    float* xdbl     = (float*)p; p += (size_t)SEQ_L * 96 * 4;               // xdbl: 1 zero pass
    ushort* xb      = (ushort*)p; p += (size_t)SEQ_L * D_MODEL * 2;
    float* xz       = (float*)p; p += (size_t)SEQ_L * 4096 * 4;
    float* u        = (float*)p; p += (size_t)SEQ_L * 2048 * 4;
    ushort* u_b     = (ushort*)p; p += (size_t)SEQ_L * 2048 * 2;
    float* dtb      = (float*)p; p += (size_t)SEQ_L * 2048 * 4;
    ushort* yb      = (ushort*)p; p += (size_t)SEQ_L * 2048 * 2;
    float* cumdt    = (float*)p; p += (size_t)SEQ_L * 2048 * 4;
    float* s_end    = (float*)p; p += (size_t)D_INNER * NCHUNK * 16 * 4;
    float* s_in     = (float*)p; p += (size_t)D_INNER * NCHUNK * 16 * 4;

    dim3 blk(256);

    // ---- weight conversions (once per launch) ----
    f32_to_bf16_kernel<<<dim3(VOCAB * D_MODEL / 4 / 256), blk, 0, stream>>>(
        emb, emb_b, VOCAB * D_MODEL / 4);
    f32_to_bf16_kernel<<<dim3(N_LAYER * 4096 * 1024 / 4 / 256), blk, 0, stream>>>(
        in_proj_w, inw_b, N_LAYER * 4096 * 1024 / 4);
    f32_to_bf16_kernel<<<dim3(N_LAYER * 1024 * 2048 / 4 / 256), blk, 0, stream>>>(
        out_proj_w, outw_b, N_LAYER * 1024 * 2048 / 4);
    xpw_convert_kernel<<<dim3(N_LAYER * 128 * 2048 / 4 / 256), blk, 0, stream>>>(
        x_proj_w, xpw_b);

    embed_kernel<<<dim3(SEQ_L), blk, 0, stream>>>(ids, emb, hidden);

    for (int i = 0; i < N_LAYER; ++i) {
        add_rmsnorm_kernel<<<dim3(SEQ_L), blk, 0, stream>>>(
            residual, hidden, norm_w + (size_t)i * D_MODEL, xb, i == 0 ? 0 : 1);

        // zero hidden + xdbl (adjacent) for the atomic split-K epilogues
        zero_kernel<<<dim3((SEQ_L * D_MODEL + SEQ_L * 96) / 4 / 256), blk, 0, stream>>>(
            hidden, (SEQ_L * D_MODEL + SEQ_L * 96) / 4);

        // xz = x @ in_proj^T : M=1024 N=4096 K=1024  (NB=32, MB=8 -> 256 blocks)
        gemm_bf16_gld_kernel<0><<<dim3(256), blk, 0, stream>>>(
            xb, inw_b + (size_t)i * 4096 * 1024, xz, 4096, 1024, 1024, 4096, 8, 1);

        conv_silu_kernel<<<dim3(SEQ_L * D_INNER / 256), blk, 0, stream>>>(
            xz, conv_w + (size_t)i * D_INNER * D_CONV, conv_b + (size_t)i * D_INNER,
            u, u_b);

        // xdbl = u @ x_proj^T : M=1024 N=96 K=2048  (NB=1, MB=8, KS=16 -> 128 blocks)
        gemm_bf16_gld_kernel<1><<<dim3(128), blk, 0, stream>>>(
            u_b, xpw_b + (size_t)i * 128 * 2048, xdbl, 96, 2048, 2048, 96, 8, 16);

        // dt = softplus(dt_r @ dt_proj^T + b)
        gemm_tn_kernel<1><<<dim3(D_INNER / 64, SEQ_L / 64), blk, 0, stream>>>(
            xdbl, dt_proj_w + (size_t)i * D_INNER * DT_RANK,
            dt_proj_b + (size_t)i * D_INNER, dtb,
            SEQ_L, D_INNER, DT_RANK, 96);

        // chunked scan
        scan_a_kernel<<<dim3(D_INNER * NCHUNK / 256), blk, 0, stream>>>(
            u, dtb, xdbl, A_log + (size_t)i * D_INNER * D_STATE, xz, cumdt, s_end);
        scan_b_kernel<<<dim3(D_INNER * 16 / 256), blk, 0, stream>>>(
            s_end, cumdt, A_log + (size_t)i * D_INNER * D_STATE, s_in);
        scan_c_kernel<<<dim3(SEQ_L * D_INNER / 256), blk, 0, stream>>>(
            u, xdbl, A_log + (size_t)i * D_INNER * D_STATE,
            Dv + (size_t)i * D_INNER, xz, cumdt, s_in, yb);

        // hidden = y @ out_proj^T : M=1024 N=1024 K=2048 (NB=8, MB=8, KS=4 -> 256 blocks)
        gemm_bf16_gld_kernel<1><<<dim3(256), blk, 0, stream>>>(
            yb, outw_b + (size_t)i * 1024 * 2048, hidden, 1024, 2048, 2048, 1024, 8, 4);
    }

    add_rmsnorm_kernel<<<dim3(SEQ_L), blk, 0, stream>>>(
        residual, hidden, norm_f_w, xb, 1);

    // logits = hf @ emb^T : M=1024 N=50280 K=1024 (NB=393, MB=8 -> 3144 blocks)
    gemm_bf16_gld_kernel<0><<<dim3(3144), blk, 0, stream>>>(
        xb, emb_b, out, VOCAB, 1024, 1024, VOCAB, 8, 1);
}

// Round 7
// 801.391 us; speedup vs baseline: 6.2625x; 1.0557x over previous
//
#include <hip/hip_runtime.h>
#include <hip/hip_bf16.h>

#define D_MODEL 1024
#define N_LAYER 4
#define D_INNER 2048
#define D_STATE 16
#define D_CONV  4
#define DT_RANK 64
#define SEQ_L   1024
#define VOCAB   50280
#define VOCAB_PAD 50304   // 393*128
#define NCHUNK  32
#define CLEN    32

typedef __attribute__((ext_vector_type(8))) short short8;
typedef __attribute__((ext_vector_type(4))) float f32x4;

typedef __attribute__((address_space(1))) const unsigned GUint;
typedef __attribute__((address_space(3))) unsigned LUint;

__device__ __forceinline__ float silu_f(float x) {
    return x / (1.0f + __expf(-x));
}
__device__ __forceinline__ float softplus_f(float x) {
    return fmaxf(x, 0.0f) + log1pf(__expf(-fabsf(x)));
}
__device__ __forceinline__ ushort f2bf(float f) {
    union { float f; unsigned u; } uf; uf.f = f;
    unsigned r = uf.u + 0x7FFF + ((uf.u >> 16) & 1);   // RNE
    return (ushort)(r >> 16);
}

// ---------------- fp32 -> bf16 bulk convert ----------------
__global__ void f32_to_bf16_kernel(const float* __restrict__ in,
                                   ushort* __restrict__ out, int n4) {
    int i = blockIdx.x * 256 + threadIdx.x;
    if (i >= n4) return;
    float4 v = *(const float4*)(in + (size_t)i * 4);
    ushort4 o;
    o.x = f2bf(v.x); o.y = f2bf(v.y); o.z = f2bf(v.z); o.w = f2bf(v.w);
    *(ushort4*)(out + (size_t)i * 4) = o;
}

// x_proj weights: (4,96,2048) fp32 -> (4,128,2048) bf16 with zero-filled pad rows
__global__ void xpw_convert_kernel(const float* __restrict__ src,
                                   ushort* __restrict__ dst) {
    int q = blockIdx.x * 256 + threadIdx.x;   // quad index, total 4*128*512
    int layer = q / (128 * 512);
    int rq    = q % (128 * 512);
    int row   = rq / 512;
    int cq    = rq % 512;
    ushort4 o;
    if (row < 96) {
        float4 v = *(const float4*)(src + ((size_t)layer * 96 + row) * 2048 + cq * 4);
        o.x = f2bf(v.x); o.y = f2bf(v.y); o.z = f2bf(v.z); o.w = f2bf(v.w);
    } else {
        o.x = o.y = o.z = o.w = 0;
    }
    *(ushort4*)(dst + (size_t)q * 4) = o;
}

// ---------------- embedding gather (writes part slot 0) ----------------
__global__ void embed_kernel(const int* __restrict__ ids,
                             const float* __restrict__ emb,
                             float* __restrict__ hidden) {
    int l = blockIdx.x;
    int t = threadIdx.x;
    int id = ids[l];
    float4 v = *(const float4*)(emb + (size_t)id * D_MODEL + t * 4);
    *(float4*)(hidden + (size_t)l * D_MODEL + t * 4) = v;
}

// ---------------- residual add + RMSNorm -> bf16 x ----------------
// res = (add? res : 0) + sum_{s<nparts} part[s]; xout = rmsnorm(res)*w
__global__ void add_rmsnorm_kernel(float* __restrict__ res,
                                   const float* __restrict__ part,
                                   const float* __restrict__ w,
                                   ushort* __restrict__ xout,
                                   int add, int nparts) {
    int l = blockIdx.x;
    int t = threadIdx.x;
    size_t base = (size_t)l * D_MODEL + t * 4;
    float4 r;
    if (add) r = *(const float4*)(res + base);
    else     r = make_float4(0.f, 0.f, 0.f, 0.f);
    for (int s = 0; s < nparts; ++s) {
        float4 hv = *(const float4*)(part + (size_t)s * SEQ_L * D_MODEL + base);
        r.x += hv.x; r.y += hv.y; r.z += hv.z; r.w += hv.w;
    }
    *(float4*)(res + base) = r;
    float ss = r.x * r.x + r.y * r.y + r.z * r.z + r.w * r.w;
    #pragma unroll
    for (int off = 32; off > 0; off >>= 1) ss += __shfl_down(ss, off, 64);
    __shared__ float sred[4];
    if ((t & 63) == 0) sred[t >> 6] = ss;
    __syncthreads();
    float tot = sred[0] + sred[1] + sred[2] + sred[3];
    float scale = rsqrtf(tot * (1.0f / (float)D_MODEL) + 1e-5f);
    float4 wv = *(const float4*)(w + t * 4);
    ushort4 o;
    o.x = f2bf(r.x * scale * wv.x);
    o.y = f2bf(r.y * scale * wv.y);
    o.z = f2bf(r.z * scale * wv.z);
    o.w = f2bf(r.w * scale * wv.w);
    *(ushort4*)(xout + base) = o;
}

// ---------------- bf16 MFMA TN GEMM, global_load_lds staging ----------------
// Linear LDS [128][32], double-buffered, 1 barrier/K-step. XCD-banded decode.
// Bank-conflict fix (rule #21): global source chunk pre-swizzled by
// ((lane>>3)&3); ds_read address XORs the same pattern -> 2-way (free).
// SPLIT=1: K-split partial outputs to C + ks*pstride (non-atomic).
// W rows must be readable up to padded N (pad rows zero-filled); M%128==0.
template<int SPLIT>
__global__ void gemm_bf16_gld_kernel(const ushort* __restrict__ A,
                                     const ushort* __restrict__ W,
                                     float* __restrict__ C,
                                     int N, int K, int lda, int ldc,
                                     int MB, int KS, int pstride) {
    __shared__ ushort As[2][128][32];
    __shared__ ushort Ws[2][128][32];
    const int t  = threadIdx.x;
    const int T  = gridDim.x >> 3;
    const int id = blockIdx.x;
    const int j  = (id & 7) * T + (id >> 3);
    const int ks  = j % KS;
    const int rem = j / KS;
    const int m0 = (rem % MB) * 128;
    const int n0 = (rem / MB) * 128;
    const int kchunk = K / KS;
    const int kbeg = ks * kchunk;
    const int kend = kbeg + kchunk;

    const int lane = t & 63;
    const int w    = t >> 6;                 // wave 0..3
    // staging: wave w covers rows w*16 + (lane>>2) (+64); source 16B chunk is
    // swizzled: chunk = (lane&3) ^ ((lane>>3)&3)  [row-dependent XOR]
    const int srow = w * 16 + (lane >> 2);
    const int scol = (((lane & 3) ^ ((lane >> 3) & 3)) * 8);   // elements
    const ushort* Ag0 = A + (size_t)(m0 + srow) * lda + scol;
    const ushort* Ag1 = A + (size_t)(m0 + srow + 64) * lda + scol;
    const ushort* Wg0 = W + (size_t)(n0 + srow) * K + scol;
    const ushort* Wg1 = W + (size_t)(n0 + srow + 64) * K + scol;

    const int wm = (t >> 7) & 1;
    const int wn = (t >> 6) & 1;
    const int lr = lane & 15;
    const int lk = lane >> 4;
    const int swz = (lr >> 1) & 3;           // read-side XOR pattern

    f32x4 acc[4][4] = {};

#define STAGE_GLD(buf, kk)                                                        \
    do {                                                                          \
        __builtin_amdgcn_global_load_lds((GUint*)(Ag0 + (kk)),                    \
            (LUint*)&As[buf][w * 16][0], 16, 0, 0);                               \
        __builtin_amdgcn_global_load_lds((GUint*)(Ag1 + (kk)),                    \
            (LUint*)&As[buf][64 + w * 16][0], 16, 0, 0);                          \
        __builtin_amdgcn_global_load_lds((GUint*)(Wg0 + (kk)),                    \
            (LUint*)&Ws[buf][w * 16][0], 16, 0, 0);                               \
        __builtin_amdgcn_global_load_lds((GUint*)(Wg1 + (kk)),                    \
            (LUint*)&Ws[buf][64 + w * 16][0], 16, 0, 0);                          \
    } while (0)

    STAGE_GLD(0, kbeg);
    int buf = 0;
    for (int k0 = kbeg;;) {
        __syncthreads();   // vmcnt(0)+lgkmcnt(0)+barrier: buf ready
        const bool more = (k0 + 32) < kend;
        if (more) STAGE_GLD(buf ^ 1, k0 + 32);

        short8 af[4], bfr[4];
        #pragma unroll
        for (int m = 0; m < 4; ++m)
            af[m] = *(const short8*)&As[buf][wm * 64 + m * 16 + lr][(lk ^ swz) * 8];
        #pragma unroll
        for (int n = 0; n < 4; ++n)
            bfr[n] = *(const short8*)&Ws[buf][wn * 64 + n * 16 + lr][(lk ^ swz) * 8];
        #pragma unroll
        for (int m = 0; m < 4; ++m)
            #pragma unroll
            for (int n = 0; n < 4; ++n)
                acc[m][n] = __builtin_amdgcn_mfma_f32_16x16x32_bf16(
                    af[m], bfr[n], acc[m][n], 0, 0, 0);

        if (!more) break;
        buf ^= 1;
        k0 += 32;
    }
#undef STAGE_GLD

    float* Cp = SPLIT ? (C + (size_t)ks * pstride) : C;
    #pragma unroll
    for (int m = 0; m < 4; ++m) {
        const int row = m0 + wm * 64 + m * 16 + lk * 4;
        #pragma unroll
        for (int n = 0; n < 4; ++n) {
            const int col = n0 + wn * 64 + n * 16 + lr;
            if (col < N) {
                #pragma unroll
                for (int r = 0; r < 4; ++r)
                    Cp[(size_t)(row + r) * ldc + col] = acc[m][n][r];
            }
        }
    }
}

// ---------------- xdbl 16-partial reduce ----------------
__global__ void xdbl_reduce_kernel(const float* __restrict__ part,
                                   float* __restrict__ out) {
    int i = blockIdx.x * 256 + threadIdx.x;   // quad index, 24576 total
    float4 acc = make_float4(0.f, 0.f, 0.f, 0.f);
    #pragma unroll
    for (int s = 0; s < 16; ++s) {
        float4 v = *(const float4*)(part + (size_t)s * SEQ_L * 96 + (size_t)i * 4);
        acc.x += v.x; acc.y += v.y; acc.z += v.z; acc.w += v.w;
    }
    *(float4*)(out + (size_t)i * 4) = acc;
}

// ---------------- fp32 TN GEMM (dt_proj only) ----------------
template<int EPI>
__global__ void gemm_tn_kernel(const float* __restrict__ A,
                               const float* __restrict__ W,
                               const float* __restrict__ bias,
                               float* __restrict__ C,
                               int M, int N, int K, int lda) {
    __shared__ float As[16][68];
    __shared__ float Ws[16][68];
    const int t  = threadIdx.x;
    const int m0 = blockIdx.y * 64;
    const int n0 = blockIdx.x * 64;
    const int lrow = t >> 2;
    const int lkq  = (t & 3) * 4;
    const int tx = t & 15;
    const int ty = t >> 4;

    const float* Arow = A + (size_t)(m0 + lrow) * lda;
    const int   wr    = n0 + lrow;
    const bool  wvalid = wr < N;
    const float* Wrow = W + (size_t)(wvalid ? wr : 0) * K;

    float acc[4][4] = {};
    for (int k0 = 0; k0 < K; k0 += 16) {
        float4 av = *(const float4*)(Arow + k0 + lkq);
        float4 wv = wvalid ? *(const float4*)(Wrow + k0 + lkq)
                           : make_float4(0.f, 0.f, 0.f, 0.f);
        As[lkq + 0][lrow] = av.x; As[lkq + 1][lrow] = av.y;
        As[lkq + 2][lrow] = av.z; As[lkq + 3][lrow] = av.w;
        Ws[lkq + 0][lrow] = wv.x; Ws[lkq + 1][lrow] = wv.y;
        Ws[lkq + 2][lrow] = wv.z; Ws[lkq + 3][lrow] = wv.w;
        __syncthreads();
        #pragma unroll
        for (int kk = 0; kk < 16; ++kk) {
            float4 a = *(const float4*)&As[kk][ty * 4];
            float4 b = *(const float4*)&Ws[kk][tx * 4];
            #pragma unroll
            for (int i = 0; i < 4; ++i) {
                float ai = (i == 0) ? a.x : (i == 1) ? a.y : (i == 2) ? a.z : a.w;
                acc[i][0] = fmaf(ai, b.x, acc[i][0]);
                acc[i][1] = fmaf(ai, b.y, acc[i][1]);
                acc[i][2] = fmaf(ai, b.z, acc[i][2]);
                acc[i][3] = fmaf(ai, b.w, acc[i][3]);
            }
        }
        __syncthreads();
    }

    const int colb = n0 + tx * 4;
    if (colb < N) {
        #pragma unroll
        for (int i = 0; i < 4; ++i) {
            int row = m0 + ty * 4 + i;
            float4 v = make_float4(acc[i][0], acc[i][1], acc[i][2], acc[i][3]);
            if (EPI == 1) {
                v.x = softplus_f(v.x + bias[colb + 0]);
                v.y = softplus_f(v.y + bias[colb + 1]);
                v.z = softplus_f(v.z + bias[colb + 2]);
                v.w = softplus_f(v.w + bias[colb + 3]);
            }
            *(float4*)(C + (size_t)row * N + colb) = v;
        }
    }
}

// ---------------- depthwise causal conv (k=4) + silu ----------------
__global__ void conv_silu_kernel(const float* __restrict__ xz,
                                 const float* __restrict__ cw,
                                 const float* __restrict__ cb,
                                 float* __restrict__ u,
                                 ushort* __restrict__ u_b) {
    int idx = blockIdx.x * 256 + threadIdx.x;
    int l = idx >> 11;
    int c = idx & 2047;
    float acc = cb[c];
    float w0 = cw[c * 4 + 0], w1 = cw[c * 4 + 1], w2 = cw[c * 4 + 2], w3 = cw[c * 4 + 3];
    if (l >= 3) acc = fmaf(xz[(size_t)(l - 3) * 4096 + c], w0, acc);
    if (l >= 2) acc = fmaf(xz[(size_t)(l - 2) * 4096 + c], w1, acc);
    if (l >= 1) acc = fmaf(xz[(size_t)(l - 1) * 4096 + c], w2, acc);
    acc = fmaf(xz[(size_t)l * 4096 + c], w3, acc);
    float s = silu_f(acc);
    u[idx] = s;
    u_b[idx] = f2bf(s);
}

// ---------------- chunked selective scan ----------------
__global__ void scan_a_kernel(const float* __restrict__ u,
                              const float* __restrict__ dt,
                              const float* __restrict__ xdbl,
                              const float* __restrict__ A_log,
                              float* __restrict__ yloc,     // stride 4096 (xz xp half)
                              float* __restrict__ cumdt,    // [l][d]
                              float* __restrict__ s_end) {  // [d][c][n]
    const int idx = blockIdx.x * 256 + threadIdx.x;   // 65536
    const int d = idx & 2047;
    const int c = idx >> 11;

    float Aa[16];
    #pragma unroll
    for (int q = 0; q < 4; ++q) {
        float4 al = *(const float4*)(A_log + (size_t)d * 16 + q * 4);
        Aa[q * 4 + 0] = -__expf(al.x);
        Aa[q * 4 + 1] = -__expf(al.y);
        Aa[q * 4 + 2] = -__expf(al.z);
        Aa[q * 4 + 3] = -__expf(al.w);
    }

    float s[16];
    #pragma unroll
    for (int n = 0; n < 16; ++n) s[n] = 0.0f;
    float cd = 0.0f;

    const int l0 = c * CLEN;
    for (int i = 0; i < CLEN; ++i) {
        const int l = l0 + i;
        const float dtl = dt[(size_t)l * 2048 + d];
        const float ul  = u[(size_t)l * 2048 + d];
        float Bn[16], Cn[16];
        const float* xbp = xdbl + (size_t)l * 96;
        *(float4*)&Bn[0]  = *(const float4*)(xbp + 64);
        *(float4*)&Bn[4]  = *(const float4*)(xbp + 68);
        *(float4*)&Bn[8]  = *(const float4*)(xbp + 72);
        *(float4*)&Bn[12] = *(const float4*)(xbp + 76);
        *(float4*)&Cn[0]  = *(const float4*)(xbp + 80);
        *(float4*)&Cn[4]  = *(const float4*)(xbp + 84);
        *(float4*)&Cn[8]  = *(const float4*)(xbp + 88);
        *(float4*)&Cn[12] = *(const float4*)(xbp + 92);
        cd += dtl;
        const float dtu = dtl * ul;
        float y = 0.0f;
        #pragma unroll
        for (int n = 0; n < 16; ++n) {
            float dA = __expf(dtl * Aa[n]);
            s[n] = fmaf(s[n], dA, dtu * Bn[n]);
            y = fmaf(s[n], Cn[n], y);
        }
        yloc[(size_t)l * 4096 + d] = y;
        cumdt[(size_t)l * 2048 + d] = cd;
    }
    float* se = s_end + ((size_t)d * NCHUNK + c) * 16;
    #pragma unroll
    for (int q = 0; q < 4; ++q)
        *(float4*)(se + q * 4) = make_float4(s[q * 4], s[q * 4 + 1], s[q * 4 + 2], s[q * 4 + 3]);
}

__global__ void scan_b_kernel(const float* __restrict__ s_end,
                              const float* __restrict__ cumdt,
                              const float* __restrict__ A_log,
                              float* __restrict__ s_in) {
    const int idx = blockIdx.x * 256 + threadIdx.x;   // 32768
    const int d = idx >> 4;
    const int n = idx & 15;
    const float Aa = -__expf(A_log[(size_t)d * 16 + n]);
    float s = 0.0f;
    #pragma unroll
    for (int c = 0; c < NCHUNK; ++c) {
        s_in[((size_t)d * NCHUNK + c) * 16 + n] = s;
        const float tot = cumdt[(size_t)(c * CLEN + CLEN - 1) * 2048 + d];
        s = s_end[((size_t)d * NCHUNK + c) * 16 + n] + __expf(Aa * tot) * s;
    }
}

__global__ void scan_c_kernel(const float* __restrict__ u,
                              const float* __restrict__ xdbl,
                              const float* __restrict__ A_log,
                              const float* __restrict__ Dv,
                              const float* __restrict__ xz,
                              const float* __restrict__ cumdt,
                              const float* __restrict__ s_in,
                              ushort* __restrict__ yb) {
    const int idx = blockIdx.x * 256 + threadIdx.x;   // l*2048+d
    const int l = idx >> 11;
    const int d = idx & 2047;
    const int c = l >> 5;   // CLEN=32

    const float cd = cumdt[idx];
    const float ul = u[idx];
    const float yv = xz[(size_t)l * 4096 + d];
    const float zv = xz[(size_t)l * 4096 + 2048 + d];
    const float* Cp = xdbl + (size_t)l * 96 + 80;
    const float* si = s_in + ((size_t)d * NCHUNK + c) * 16;

    float corr = 0.0f;
    #pragma unroll
    for (int q = 0; q < 4; ++q) {
        float4 al = *(const float4*)(A_log + (size_t)d * 16 + q * 4);
        float4 cv = *(const float4*)(Cp + q * 4);
        float4 sv = *(const float4*)(si + q * 4);
        corr = fmaf(cv.x * __expf(-__expf(al.x) * cd), sv.x, corr);
        corr = fmaf(cv.y * __expf(-__expf(al.y) * cd), sv.y, corr);
        corr = fmaf(cv.z * __expf(-__expf(al.z) * cd), sv.z, corr);
        corr = fmaf(cv.w * __expf(-__expf(al.w) * cd), sv.w, corr);
    }
    const float y = (yv + corr + Dv[d] * ul) * silu_f(zv);
    yb[idx] = f2bf(y);
}

extern "C" void kernel_launch(void* const* d_in, const int* in_sizes, int n_in,
                              void* d_out, int out_size, void* d_ws, size_t ws_size,
                              hipStream_t stream) {
    const int*   ids        = (const int*)d_in[0];
    const float* emb        = (const float*)d_in[1];
    const float* norm_w     = (const float*)d_in[2];
    const float* in_proj_w  = (const float*)d_in[3];
    const float* conv_w     = (const float*)d_in[4];
    const float* conv_b     = (const float*)d_in[5];
    const float* x_proj_w   = (const float*)d_in[6];
    const float* dt_proj_w  = (const float*)d_in[7];
    const float* dt_proj_b  = (const float*)d_in[8];
    const float* A_log      = (const float*)d_in[9];
    const float* Dv         = (const float*)d_in[10];
    const float* out_proj_w = (const float*)d_in[11];
    const float* norm_f_w   = (const float*)d_in[12];
    float* out = (float*)d_out;

    // ---- workspace layout ----
    char* p = (char*)d_ws;
    ushort* emb_b  = (ushort*)p; p += (size_t)VOCAB_PAD * D_MODEL * 2;      // 103 MB
    ushort* inw_b  = (ushort*)p; p += (size_t)N_LAYER * 4096 * 1024 * 2;    // 33.6 MB
    ushort* outw_b = (ushort*)p; p += (size_t)N_LAYER * 1024 * 2048 * 2;    // 16.8 MB
    ushort* xpw_b  = (ushort*)p; p += (size_t)N_LAYER * 128 * 2048 * 2;     //  2.1 MB (padded)
    float* residual = (float*)p; p += (size_t)SEQ_L * D_MODEL * 4;
    float* hpart    = (float*)p; p += (size_t)4 * SEQ_L * D_MODEL * 4;      // 16.8 MB (4 partials)
    float* xdpart   = (float*)p; p += (size_t)16 * SEQ_L * 96 * 4;          //  6.3 MB (16 partials)
    float* xdbl     = (float*)p; p += (size_t)SEQ_L * 96 * 4;
    ushort* xb      = (ushort*)p; p += (size_t)SEQ_L * D_MODEL * 2;
    float* xz       = (float*)p; p += (size_t)SEQ_L * 4096 * 4;
    float* u        = (float*)p; p += (size_t)SEQ_L * 2048 * 4;
    ushort* u_b     = (ushort*)p; p += (size_t)SEQ_L * 2048 * 2;
    float* dtb      = (float*)p; p += (size_t)SEQ_L * 2048 * 4;
    ushort* yb      = (ushort*)p; p += (size_t)SEQ_L * 2048 * 2;
    float* cumdt    = (float*)p; p += (size_t)SEQ_L * 2048 * 4;
    float* s_end    = (float*)p; p += (size_t)D_INNER * NCHUNK * 16 * 4;
    float* s_in     = (float*)p; p += (size_t)D_INNER * NCHUNK * 16 * 4;

    dim3 blk(256);

    // ---- weight conversions (once per launch) ----
    f32_to_bf16_kernel<<<dim3(VOCAB * D_MODEL / 4 / 256), blk, 0, stream>>>(
        emb, emb_b, VOCAB * D_MODEL / 4);
    f32_to_bf16_kernel<<<dim3(N_LAYER * 4096 * 1024 / 4 / 256), blk, 0, stream>>>(
        in_proj_w, inw_b, N_LAYER * 4096 * 1024 / 4);
    f32_to_bf16_kernel<<<dim3(N_LAYER * 1024 * 2048 / 4 / 256), blk, 0, stream>>>(
        out_proj_w, outw_b, N_LAYER * 1024 * 2048 / 4);
    xpw_convert_kernel<<<dim3(N_LAYER * 128 * 2048 / 4 / 256), blk, 0, stream>>>(
        x_proj_w, xpw_b);

    // hidden lives in hpart slot 0 before layer 0
    embed_kernel<<<dim3(SEQ_L), blk, 0, stream>>>(ids, emb, hpart);

    for (int i = 0; i < N_LAYER; ++i) {
        // residual (+)= sum(partials) ; x = rmsnorm(residual)
        add_rmsnorm_kernel<<<dim3(SEQ_L), blk, 0, stream>>>(
            residual, hpart, norm_w + (size_t)i * D_MODEL, xb,
            i == 0 ? 0 : 1, i == 0 ? 1 : 4);

        // xz = x @ in_proj^T : M=1024 N=4096 K=1024  (NB=32, MB=8 -> 256 blocks)
        gemm_bf16_gld_kernel<0><<<dim3(256), blk, 0, stream>>>(
            xb, inw_b + (size_t)i * 4096 * 1024, xz, 4096, 1024, 1024, 4096, 8, 1, 0);

        conv_silu_kernel<<<dim3(SEQ_L * D_INNER / 256), blk, 0, stream>>>(
            xz, conv_w + (size_t)i * D_INNER * D_CONV, conv_b + (size_t)i * D_INNER,
            u, u_b);

        // xdbl partials: M=1024 N=96 K=2048  (NB=1, MB=8, KS=16 -> 128 blocks)
        gemm_bf16_gld_kernel<1><<<dim3(128), blk, 0, stream>>>(
            u_b, xpw_b + (size_t)i * 128 * 2048, xdpart, 96, 2048, 2048, 96,
            8, 16, SEQ_L * 96);
        xdbl_reduce_kernel<<<dim3(SEQ_L * 96 / 4 / 256), blk, 0, stream>>>(
            xdpart, xdbl);

        // dt = softplus(dt_r @ dt_proj^T + b)
        gemm_tn_kernel<1><<<dim3(D_INNER / 64, SEQ_L / 64), blk, 0, stream>>>(
            xdbl, dt_proj_w + (size_t)i * D_INNER * DT_RANK,
            dt_proj_b + (size_t)i * D_INNER, dtb,
            SEQ_L, D_INNER, DT_RANK, 96);

        // chunked scan
        scan_a_kernel<<<dim3(D_INNER * NCHUNK / 256), blk, 0, stream>>>(
            u, dtb, xdbl, A_log + (size_t)i * D_INNER * D_STATE, xz, cumdt, s_end);
        scan_b_kernel<<<dim3(D_INNER * 16 / 256), blk, 0, stream>>>(
            s_end, cumdt, A_log + (size_t)i * D_INNER * D_STATE, s_in);
        scan_c_kernel<<<dim3(SEQ_L * D_INNER / 256), blk, 0, stream>>>(
            u, xdbl, A_log + (size_t)i * D_INNER * D_STATE,
            Dv + (size_t)i * D_INNER, xz, cumdt, s_in, yb);

        // hidden partials = y @ out_proj^T : M=1024 N=1024 K=2048
        // (NB=8, MB=8, KS=4 -> 256 blocks), partial buffers, no atomics
        gemm_bf16_gld_kernel<1><<<dim3(256), blk, 0, stream>>>(
            yb, outw_b + (size_t)i * 1024 * 2048, hpart, 1024, 2048, 2048, 1024,
            8, 4, SEQ_L * D_MODEL);
    }

    add_rmsnorm_kernel<<<dim3(SEQ_L), blk, 0, stream>>>(
        residual, hpart, norm_f_w, xb, 1, 4);

    // logits = hf @ emb^T : M=1024 N=50280 K=1024 (NB=393, MB=8 -> 3144 blocks)
    gemm_bf16_gld_kernel<0><<<dim3(3144), blk, 0, stream>>>(
        xb, emb_b, out, VOCAB, 1024, 1024, VOCAB, 8, 1, 0);
}